// Round 8
// baseline (358.187 us; speedup 1.0000x reference)
//
#include <hip/hip_runtime.h>

#define B_     8
#define N_     2048
#define J_     1024
#define QD_    1024
#define CD_    768
#define H_     16
#define D_     64
#define INNER_ 1024

typedef __attribute__((ext_vector_type(8)))  __bf16 bf16x8;
typedef __attribute__((ext_vector_type(4)))  __bf16 bf16x4;
typedef __attribute__((ext_vector_type(4)))  float  f32x4;
typedef __attribute__((ext_vector_type(16))) float  f32x16;

__device__ __forceinline__ __bf16 to_bf16(float f) { return (__bf16)f; }

// pack two floats as bf16 pair into one dword (lo in low 16 bits) — no inline asm
__device__ __forceinline__ unsigned pack2(float lo, float hi) {
    union { __bf16 h; unsigned short u; } a, b;
    a.h = (__bf16)lo; b.h = (__bf16)hi;
    return (unsigned)a.u | ((unsigned)b.u << 16);
}

// ---------------- fp32 -> bf16 elementwise convert (vectorized) ----------------
__global__ __launch_bounds__(256)
void cvt_bf16_k(const float* __restrict__ s, __bf16* __restrict__ d, int n4)
{
    int i = blockIdx.x * 256 + threadIdx.x;
    if (i >= n4) return;
    float4 v = ((const float4*)s)[i];
    bf16x4 o;
    o[0] = (__bf16)v.x; o[1] = (__bf16)v.y; o[2] = (__bf16)v.z; o[3] = (__bf16)v.w;
    ((bf16x4*)d)[i] = o;
}

// ---------------- W[K][N] fp32 -> Wt[N][K] bf16 (LDS tile transpose, w/ scale) ----------------
__global__ __launch_bounds__(256)
void transpose_bf16(const float* __restrict__ W, __bf16* __restrict__ Wt, int K, int N, float scale)
{
    __shared__ float tile[32][33];
    const int n0 = blockIdx.x * 32;
    const int k0 = blockIdx.y * 32;
    const int tx = threadIdx.x & 31;
    const int ty = threadIdx.x >> 5;       // 0..7
#pragma unroll
    for (int r = 0; r < 32; r += 8)
        tile[ty + r][tx] = W[(size_t)(k0 + ty + r) * N + n0 + tx];
    __syncthreads();
#pragma unroll
    for (int r = 0; r < 32; r += 8)
        Wt[(size_t)(n0 + ty + r) * K + k0 + tx] = to_bf16(tile[tx][ty + r] * scale);
}

// ---------------- bf16 GEMM: C[M,N] = A[M,K] * Bt[N,K]^T, tile 128x256 ----------------
// 4 waves (2x2), per-wave 64x128 = 4x8 16x16x32 fragments. BK=32.
// 1D grid with XCD-chunked decode (nwg % 8 == 0): consecutive n-tiles of one
// A-panel stay on one XCD -> A read once from HBM, reused from L2.
// FINAL=0: bf16 row-major out. FINAL=1: fp32 out + bias.
// FINAL=3: fused KV out — col<1024: Kb row-major; col>=1024: Vt head-split
//          Vt[(b*16+h)*64 + d][J] (8B store of 4 consecutive j per lane).
template<int FINAL>
__global__ __launch_bounds__(256)
void gemm_bt(const __bf16* __restrict__ A, const __bf16* __restrict__ Bt,
             __bf16* __restrict__ Cb, __bf16* __restrict__ Cb2, float* __restrict__ Cf,
             const float* __restrict__ bias, int M, int N, int K)
{
    __shared__ __bf16 Asm[128 * 32];
    __shared__ __bf16 Bsm[256 * 32];

    const int tid = threadIdx.x;
    const int wid = tid >> 6;
    const int l   = tid & 63;
    const int lo  = l & 15, hi = l >> 4;

    // XCD-chunked bijective swizzle (requires gridDim.x % 8 == 0)
    const int nwg  = gridDim.x;
    const int work = ((int)blockIdx.x & 7) * (nwg >> 3) + ((int)blockIdx.x >> 3);
    const int gn   = N >> 8;                  // n-tiles of 256
    const int m0   = (work / gn) * 128;
    const int n0   = (work % gn) * 256;

    const int wm  = (wid >> 1) * 64, wn = (wid & 1) * 128;

    f32x4 acc[4][8] = {};

    const int srow = (l >> 2);       // 0..15 rows within a 1KB staging inst
    const int scol = (l & 3) * 8;    // k-element offset

    for (int kt = 0; kt < K; kt += 32) {
#pragma unroll
        for (int i = 0; i < 2; ++i) {
            const int rbase = wid * 32 + i * 16;
            const __bf16* ga = A + (size_t)(m0 + rbase + srow) * K + kt + scol;
            __builtin_amdgcn_global_load_lds((const __attribute__((address_space(1))) void*)ga,
                                             (__attribute__((address_space(3))) void*)&Asm[rbase * 32],
                                             16, 0, 0);
        }
#pragma unroll
        for (int i = 0; i < 4; ++i) {
            const int rbase = wid * 64 + i * 16;
            const __bf16* gb = Bt + (size_t)(n0 + rbase + srow) * K + kt + scol;
            __builtin_amdgcn_global_load_lds((const __attribute__((address_space(1))) void*)gb,
                                             (__attribute__((address_space(3))) void*)&Bsm[rbase * 32],
                                             16, 0, 0);
        }
        __syncthreads();

        bf16x8 af[4], bfr[8];
#pragma unroll
        for (int i = 0; i < 4; ++i)
            af[i]  = *(const bf16x8*)&Asm[(wm + i * 16 + lo) * 32 + hi * 8];
#pragma unroll
        for (int j = 0; j < 8; ++j)
            bfr[j] = *(const bf16x8*)&Bsm[(wn + j * 16 + lo) * 32 + hi * 8];
#pragma unroll
        for (int i = 0; i < 4; ++i)
#pragma unroll
            for (int j = 0; j < 8; ++j)
                acc[i][j] = __builtin_amdgcn_mfma_f32_16x16x32_bf16(af[i], bfr[j], acc[i][j], 0, 0, 0);
        __syncthreads();
    }

#pragma unroll
    for (int i = 0; i < 4; ++i) {
        const int row = m0 + wm + i * 16 + hi * 4;
#pragma unroll
        for (int j = 0; j < 8; ++j) {
            const int col = n0 + wn + j * 16 + lo;
            if (FINAL == 3) {
                if (col < 1024) {
#pragma unroll
                    for (int r = 0; r < 4; ++r)
                        Cb[(size_t)(row + r) * 1024 + col] = to_bf16(acc[i][j][r]);
                } else {
                    const int c2 = col - 1024;
                    const int head = c2 >> 6, d = c2 & 63;
                    const int bb = row >> 10, jj = row & 1023;
                    bf16x4 v4;
#pragma unroll
                    for (int r = 0; r < 4; ++r) v4[r] = to_bf16(acc[i][j][r]);
                    *(bf16x4*)&Cb2[(((size_t)(bb * 16 + head)) * 64 + d) * (size_t)J_ + jj] = v4;
                }
            } else {
#pragma unroll
                for (int r = 0; r < 4; ++r) {
                    if (FINAL == 1) Cf[(size_t)(row + r) * N + col] = acc[i][j][r] + bias[col];
                    else            Cb[(size_t)(row + r) * N + col] = to_bf16(acc[i][j][r]);
                }
            }
        }
    }
}

// ---------------- attention, swapped-operand 32x32 MFMA, KVBLK=64, QBLK=32/wave --------
// (unchanged from R7 — 108.9 us, MfmaUtil 27%, FETCH 33MB)
#define SEGE 544   // elements per 1088B segment

__global__ __launch_bounds__(256, 3)
void attn2(const __bf16* __restrict__ Qb, const __bf16* __restrict__ Kb,
           const __bf16* __restrict__ Vt, __bf16* __restrict__ Ob)
{
    __shared__ __bf16 sK[2][8 * SEGE];   // [64 j][64 d] segmented
    __shared__ __bf16 sV[2][8 * SEGE];   // [64 d][64 j] segmented

    const int tid = threadIdx.x;
    const int wid = tid >> 6;
    const int l   = tid & 63;
    const int lq  = l & 31;
    const int hi  = l >> 5;

    // XCD-chunked bijective swizzle: 2048 blocks = 8 XCDs x 256
    const int blk  = blockIdx.x;
    const int work = (blk & 7) * 256 + (blk >> 3);
    const int qt = work & 15;          // 0..15 (128 q-rows per block)
    const int h  = (work >> 4) & 15;
    const int b  = work >> 8;
    const int bh = b * H_ + h;

    // Q fragments (B-operand: col q = lane&31, k = d = kc*16 + hi*8 + s)
    bf16x8 qf[4];
    {
        const __bf16* qp = Qb + ((size_t)b * N_ + qt * 128 + wid * 32 + lq) * INNER_ + h * D_;
#pragma unroll
        for (int kc = 0; kc < 4; ++kc)
            qf[kc] = *(const bf16x8*)(qp + kc * 16 + hi * 8);
    }

    f32x16 accO[2] = {};           // [d-tile] : O^T fragments (32 regs)
    float lsum = 0.f;

    // staging lane geometry: within-seg row = l>>3, chunk = l&7, swizzled source chunk
    const int srow = l >> 3, schk = l & 7;
    const __bf16* ksrc = Kb + ((size_t)b * J_ + wid * 8 + srow) * INNER_ + h * D_ + ((schk ^ srow) * 8);
    const __bf16* vsrc = Vt + ((size_t)bh * D_ + wid * 8 + srow) * J_ + ((schk ^ srow) * 8);

#define STAGE_T(bb, t) do { \
    _Pragma("unroll") \
    for (int c = 0; c < 2; ++c) { \
        __builtin_amdgcn_global_load_lds((const __attribute__((address_space(1))) void*)(ksrc + ((size_t)(t) * 64 + c * 32) * INNER_), \
            (__attribute__((address_space(3))) void*)(&sK[bb][(c * 4 + wid) * SEGE]), 16, 0, 0); \
        __builtin_amdgcn_global_load_lds((const __attribute__((address_space(1))) void*)(vsrc + (size_t)(c) * 32 * J_ + (t) * 64), \
            (__attribute__((address_space(3))) void*)(&sV[bb][(c * 4 + wid) * SEGE]), 16, 0, 0); \
    } } while (0)

    STAGE_T(0, 0);
    __syncthreads();

    for (int t = 0; t < J_ / 64; ++t) {
        const int bb = t & 1;
        if (t < J_ / 64 - 1) STAGE_T(bb ^ 1, t + 1);

        const __bf16* Ks = sK[bb];
        const __bf16* Vs = sV[bb];

#pragma unroll
        for (int jsub = 0; jsub < 2; ++jsub) {
            // K fragment rows j = jsub*32 + lq ; seg addressing
            bf16x8 kf[4], vf[2][2];
            const int ksg = (jsub * 4 + (lq >> 3)) * SEGE + (lq & 7) * 64;
#pragma unroll
            for (int kc = 0; kc < 4; ++kc)
                kf[kc] = *(const bf16x8*)&Ks[ksg + (((kc * 2 + hi) ^ (lq & 7)) * 8)];
#pragma unroll
            for (int dt = 0; dt < 2; ++dt) {
                const int vsg = (dt * 4 + (lq >> 3)) * SEGE + (lq & 7) * 64;
#pragma unroll
                for (int k2 = 0; k2 < 2; ++k2)
                    vf[dt][k2] = *(const bf16x8*)&Vs[vsg + ((((jsub * 2 + k2) * 2 + hi) ^ (lq & 7)) * 8)];
            }

            // S^T[j][q] for 32 j-rows: lane col q = lq, rows j = (r&3)+8*(r>>2)+4*hi
            f32x16 s = {};
            __builtin_amdgcn_s_setprio(1);
#pragma unroll
            for (int kc = 0; kc < 4; ++kc)
                s = __builtin_amdgcn_mfma_f32_32x32x16_bf16(kf[kc], qf[kc], s, 0, 0, 0);
            __builtin_amdgcn_s_setprio(0);

            float p[16];
#pragma unroll
            for (int r = 0; r < 16; ++r)
                p[r] = __builtin_amdgcn_exp2f(s[r]);  // raw v_exp_f32; scale*log2e folded into Wq
            // pairwise tree sum (fp order fixed; log-depth dep chain)
            {
                float t0 = (p[0] + p[1]) + (p[2] + p[3]);
                float t1 = (p[4] + p[5]) + (p[6] + p[7]);
                float t2 = (p[8] + p[9]) + (p[10] + p[11]);
                float t3 = (p[12] + p[13]) + (p[14] + p[15]);
                lsum += (t0 + t1) + (t2 + t3);
            }

            // P^T fragments: B-operand slot (hi,e) of k-slot (jsub*2+k2) holds
            // P[j_local = jsub*32 + k2*16 + hi*8 + e][q]. Exchange halves via lane^32.
#pragma unroll
            for (int k2 = 0; k2 < 2; ++k2) {
                unsigned a0 = pack2(p[k2 * 8 + 0], p[k2 * 8 + 1]);   // rows {0,1}+4*hi
                unsigned a1 = pack2(p[k2 * 8 + 2], p[k2 * 8 + 3]);   // rows {2,3}+4*hi
                unsigned b0 = pack2(p[k2 * 8 + 4], p[k2 * 8 + 5]);   // rows {8,9}+4*hi
                unsigned b1 = pack2(p[k2 * 8 + 6], p[k2 * 8 + 7]);   // rows {10,11}+4*hi
                unsigned sw0 = __shfl_xor(hi ? a0 : b0, 32);
                unsigned sw1 = __shfl_xor(hi ? a1 : b1, 32);
                union { unsigned u[4]; bf16x8 v; } pu;
                pu.u[0] = hi ? sw0 : a0;     // e=0,1 : j = hi*8 + {0,1}
                pu.u[1] = hi ? sw1 : a1;     // e=2,3
                pu.u[2] = hi ? b0  : sw0;    // e=4,5
                pu.u[3] = hi ? b1  : sw1;    // e=6,7
                __builtin_amdgcn_s_setprio(1);
#pragma unroll
                for (int dt = 0; dt < 2; ++dt)
                    accO[dt] = __builtin_amdgcn_mfma_f32_32x32x16_bf16(vf[dt][k2], pu.v, accO[dt], 0, 0, 0);
                __builtin_amdgcn_s_setprio(0);
            }
        }
        __syncthreads();
    }
#undef STAGE_T

    // epilogue: merge lane-pair sums once, normalize, write O (64B-line-forming 8B stores)
    {
        float lt = lsum + __shfl_xor(lsum, 32);
        float inv = 1.f / lt;
        __bf16* op = Ob + ((size_t)b * N_ + qt * 128 + wid * 32 + lq) * INNER_ + h * D_;
#pragma unroll
        for (int dt = 0; dt < 2; ++dt)
#pragma unroll
            for (int g = 0; g < 4; ++g) {           // d = dt*32 + g*8 + hi*4 + e
                bf16x4 v4;
#pragma unroll
                for (int e = 0; e < 4; ++e) v4[e] = to_bf16(accO[dt][g * 4 + e] * inv);
                *(bf16x4*)&op[dt * 32 + g * 8 + hi * 4] = v4;
            }
    }
}

// ---------------- host ----------------
extern "C" void kernel_launch(void* const* d_in, const int* in_sizes, int n_in,
                              void* d_out, int out_size, void* d_ws, size_t ws_size,
                              hipStream_t stream)
{
    const float* x   = (const float*)d_in[0];
    const float* ctx = (const float*)d_in[1];
    const float* Wq  = (const float*)d_in[2];
    const float* Wk  = (const float*)d_in[3];
    const float* Wv  = (const float*)d_in[4];
    const float* Wo  = (const float*)d_in[5];
    const float* bo  = (const float*)d_in[6];
    float* out = (float*)d_out;

    char* w = (char*)d_ws;
    auto take = [&](size_t bytes) { char* p = w; w += bytes; return p; };
    __bf16* xb  = (__bf16*)take((size_t)B_ * N_ * QD_ * 2);      // 33.5 MB
    __bf16* cb  = (__bf16*)take((size_t)B_ * J_ * CD_ * 2);      // 12.6 MB
    __bf16* wqt = (__bf16*)take((size_t)QD_ * INNER_ * 2);
    __bf16* wkt = (__bf16*)take((size_t)CD_ * INNER_ * 2);       // wkt+wvt adjacent:
    __bf16* wvt = (__bf16*)take((size_t)CD_ * INNER_ * 2);       //  fused KV B operand
    __bf16* wot = (__bf16*)take((size_t)INNER_ * QD_ * 2);
    __bf16* Qb  = (__bf16*)take((size_t)B_ * N_ * INNER_ * 2);   // 33.5 MB
    __bf16* Kb  = (__bf16*)take((size_t)B_ * J_ * INNER_ * 2);   // 16.8 MB
    __bf16* Vt  = (__bf16*)take((size_t)B_ * J_ * INNER_ * 2);   // 16.8 MB (head-split V^T)
    __bf16* Ob  = xb;  // alias: xb is dead after the Q projection

    const float SCALE_Q = 0.125f * 1.44269504088896f;  // D^-0.5 * log2(e), folded into Wq

    cvt_bf16_k<<<(B_ * N_ * QD_) / 1024, 256, 0, stream>>>(x,   xb, (B_ * N_ * QD_) / 4);
    cvt_bf16_k<<<(B_ * J_ * CD_) / 1024, 256, 0, stream>>>(ctx, cb, (B_ * J_ * CD_) / 4);

    transpose_bf16<<<dim3(INNER_ / 32, QD_ / 32), 256, 0, stream>>>(Wq, wqt, QD_, INNER_, SCALE_Q);
    transpose_bf16<<<dim3(INNER_ / 32, CD_ / 32), 256, 0, stream>>>(Wk, wkt, CD_, INNER_, 1.f);
    transpose_bf16<<<dim3(INNER_ / 32, CD_ / 32), 256, 0, stream>>>(Wv, wvt, CD_, INNER_, 1.f);
    transpose_bf16<<<dim3(QD_ / 32, INNER_ / 32), 256, 0, stream>>>(Wo, wot, INNER_, QD_, 1.f);

    // Q proj: M=16384, N=1024 -> 128x4 tiles = 512 blocks
    gemm_bt<0><<<512, 256, 0, stream>>>(xb, wqt, Qb, nullptr, nullptr, nullptr, B_ * N_, INNER_, QD_);
    // fused K+V proj: M=8192, N=2048 (wkt||wvt) -> 64x8 tiles = 512 blocks
    gemm_bt<3><<<512, 256, 0, stream>>>(cb, wkt, Kb, Vt, nullptr, nullptr, B_ * J_, 2 * INNER_, CD_);

    attn2<<<(N_ / 128) * H_ * B_, 256, 0, stream>>>(Qb, Kb, Vt, Ob);

    // O proj: M=16384, N=1024 -> 512 blocks, fp32 + bias epilogue
    gemm_bt<1><<<512, 256, 0, stream>>>(Ob, wot, nullptr, nullptr, out, bo, B_ * N_, QD_, INNER_);
}

// Round 9
// 290.255 us; speedup vs baseline: 1.2340x; 1.2340x over previous
//
#include <hip/hip_runtime.h>

#define B_     8
#define N_     2048
#define J_     1024
#define QD_    1024
#define CD_    768
#define H_     16
#define D_     64
#define INNER_ 1024

typedef __attribute__((ext_vector_type(8)))  __bf16 bf16x8;
typedef __attribute__((ext_vector_type(4)))  __bf16 bf16x4;
typedef __attribute__((ext_vector_type(4)))  float  f32x4;
typedef __attribute__((ext_vector_type(16))) float  f32x16;

__device__ __forceinline__ __bf16 to_bf16(float f) { return (__bf16)f; }

// pack two floats as bf16 pair into one dword (lo in low 16 bits) — no inline asm
__device__ __forceinline__ unsigned pack2(float lo, float hi) {
    union { __bf16 h; unsigned short u; } a, b;
    a.h = (__bf16)lo; b.h = (__bf16)hi;
    return (unsigned)a.u | ((unsigned)b.u << 16);
}

// ---------------- fp32 -> bf16 elementwise convert (vectorized) ----------------
__global__ __launch_bounds__(256)
void cvt_bf16_k(const float* __restrict__ s, __bf16* __restrict__ d, int n4)
{
    int i = blockIdx.x * 256 + threadIdx.x;
    if (i >= n4) return;
    float4 v = ((const float4*)s)[i];
    bf16x4 o;
    o[0] = (__bf16)v.x; o[1] = (__bf16)v.y; o[2] = (__bf16)v.z; o[3] = (__bf16)v.w;
    ((bf16x4*)d)[i] = o;
}

// ---------------- W[K][N] fp32 -> Wt[N][K] bf16 (LDS tile transpose, w/ scale) ----------------
__global__ __launch_bounds__(256)
void transpose_bf16(const float* __restrict__ W, __bf16* __restrict__ Wt, int K, int N, float scale)
{
    __shared__ float tile[32][33];
    const int n0 = blockIdx.x * 32;
    const int k0 = blockIdx.y * 32;
    const int tx = threadIdx.x & 31;
    const int ty = threadIdx.x >> 5;       // 0..7
#pragma unroll
    for (int r = 0; r < 32; r += 8)
        tile[ty + r][tx] = W[(size_t)(k0 + ty + r) * N + n0 + tx];
    __syncthreads();
#pragma unroll
    for (int r = 0; r < 32; r += 8)
        Wt[(size_t)(n0 + ty + r) * K + k0 + tx] = to_bf16(tile[tx][ty + r] * scale);
}

// ---------------- bf16 GEMM: C[M,N] = A[M,K] * Bt[N,K]^T, tile 128x128 (m97) -------
// 4 waves (2x2), per-wave 64x64 = 4x4 16x16x32 fragments. BK=32.
// 1D grid, XCD-chunked bijective decode (gridDim % 8 == 0).
// FINAL=0: bf16 row-major out. FINAL=1: fp32 out + bias.
// FINAL=3: fused KV out — col<1024: Kb row-major; col>=1024: Vt head-split
//          Vt[(b*16+h)*64 + d][J] (8B store of 4 consecutive j per lane).
template<int FINAL>
__global__ __launch_bounds__(256)
void gemm_bt(const __bf16* __restrict__ A, const __bf16* __restrict__ Bt,
             __bf16* __restrict__ Cb, __bf16* __restrict__ Cb2, float* __restrict__ Cf,
             const float* __restrict__ bias, int M, int N, int K)
{
    __shared__ __bf16 Asm[128 * 32];
    __shared__ __bf16 Bsm[128 * 32];

    const int tid = threadIdx.x;
    const int wid = tid >> 6;
    const int l   = tid & 63;
    const int lo  = l & 15, hi = l >> 4;

    // XCD-chunked bijective swizzle
    const int nwg  = gridDim.x;
    const int work = ((int)blockIdx.x & 7) * (nwg >> 3) + ((int)blockIdx.x >> 3);
    const int gn   = N >> 7;                  // n-tiles of 128
    const int m0   = (work / gn) * 128;
    const int n0   = (work % gn) * 128;

    const int wm  = (wid >> 1) * 64, wn = (wid & 1) * 64;

    f32x4 acc[4][4] = {};

    const int srow = (l >> 2);       // 0..15 rows within a 1KB staging inst
    const int scol = (l & 3) * 8;    // k-element offset

    for (int kt = 0; kt < K; kt += 32) {
#pragma unroll
        for (int i = 0; i < 2; ++i) {
            const int rbase = wid * 32 + i * 16;
            const __bf16* ga = A  + (size_t)(m0 + rbase + srow) * K + kt + scol;
            __builtin_amdgcn_global_load_lds((const __attribute__((address_space(1))) void*)ga,
                                             (__attribute__((address_space(3))) void*)&Asm[rbase * 32],
                                             16, 0, 0);
            const __bf16* gb = Bt + (size_t)(n0 + rbase + srow) * K + kt + scol;
            __builtin_amdgcn_global_load_lds((const __attribute__((address_space(1))) void*)gb,
                                             (__attribute__((address_space(3))) void*)&Bsm[rbase * 32],
                                             16, 0, 0);
        }
        __syncthreads();

        bf16x8 af[4], bfr[4];
#pragma unroll
        for (int i = 0; i < 4; ++i) {
            af[i]  = *(const bf16x8*)&Asm[(wm + i * 16 + lo) * 32 + hi * 8];
            bfr[i] = *(const bf16x8*)&Bsm[(wn + i * 16 + lo) * 32 + hi * 8];
        }
#pragma unroll
        for (int i = 0; i < 4; ++i)
#pragma unroll
            for (int j = 0; j < 4; ++j)
                acc[i][j] = __builtin_amdgcn_mfma_f32_16x16x32_bf16(af[i], bfr[j], acc[i][j], 0, 0, 0);
        __syncthreads();
    }

#pragma unroll
    for (int i = 0; i < 4; ++i) {
        const int row = m0 + wm + i * 16 + hi * 4;
#pragma unroll
        for (int j = 0; j < 4; ++j) {
            const int col = n0 + wn + j * 16 + lo;
            if (FINAL == 3) {
                if (col < 1024) {
#pragma unroll
                    for (int r = 0; r < 4; ++r)
                        Cb[(size_t)(row + r) * 1024 + col] = to_bf16(acc[i][j][r]);
                } else {
                    const int c2 = col - 1024;
                    const int head = c2 >> 6, d = c2 & 63;
                    const int bb = row >> 10, jj = row & 1023;
                    bf16x4 v4;
#pragma unroll
                    for (int r = 0; r < 4; ++r) v4[r] = to_bf16(acc[i][j][r]);
                    *(bf16x4*)&Cb2[(((size_t)(bb * 16 + head)) * 64 + d) * (size_t)J_ + jj] = v4;
                }
            } else {
#pragma unroll
                for (int r = 0; r < 4; ++r) {
                    if (FINAL == 1) Cf[(size_t)(row + r) * N + col] = acc[i][j][r] + bias[col];
                    else            Cb[(size_t)(row + r) * N + col] = to_bf16(acc[i][j][r]);
                }
            }
        }
    }
}

// ---------------- attention, swapped-operand 32x32 MFMA, KVBLK=64, QBLK=32/wave --------
// (unchanged from R7 — 108.9 us, MfmaUtil 27%, FETCH 33MB)
#define SEGE 544   // elements per 1088B segment

__global__ __launch_bounds__(256, 3)
void attn2(const __bf16* __restrict__ Qb, const __bf16* __restrict__ Kb,
           const __bf16* __restrict__ Vt, __bf16* __restrict__ Ob)
{
    __shared__ __bf16 sK[2][8 * SEGE];   // [64 j][64 d] segmented
    __shared__ __bf16 sV[2][8 * SEGE];   // [64 d][64 j] segmented

    const int tid = threadIdx.x;
    const int wid = tid >> 6;
    const int l   = tid & 63;
    const int lq  = l & 31;
    const int hi  = l >> 5;

    // XCD-chunked bijective swizzle: 2048 blocks = 8 XCDs x 256
    const int blk  = blockIdx.x;
    const int work = (blk & 7) * 256 + (blk >> 3);
    const int qt = work & 15;          // 0..15 (128 q-rows per block)
    const int h  = (work >> 4) & 15;
    const int b  = work >> 8;
    const int bh = b * H_ + h;

    // Q fragments (B-operand: col q = lane&31, k = d = kc*16 + hi*8 + s)
    bf16x8 qf[4];
    {
        const __bf16* qp = Qb + ((size_t)b * N_ + qt * 128 + wid * 32 + lq) * INNER_ + h * D_;
#pragma unroll
        for (int kc = 0; kc < 4; ++kc)
            qf[kc] = *(const bf16x8*)(qp + kc * 16 + hi * 8);
    }

    f32x16 accO[2] = {};           // [d-tile] : O^T fragments (32 regs)
    float lsum = 0.f;

    // staging lane geometry: within-seg row = l>>3, chunk = l&7, swizzled source chunk
    const int srow = l >> 3, schk = l & 7;
    const __bf16* ksrc = Kb + ((size_t)b * J_ + wid * 8 + srow) * INNER_ + h * D_ + ((schk ^ srow) * 8);
    const __bf16* vsrc = Vt + ((size_t)bh * D_ + wid * 8 + srow) * J_ + ((schk ^ srow) * 8);

#define STAGE_T(bb, t) do { \
    _Pragma("unroll") \
    for (int c = 0; c < 2; ++c) { \
        __builtin_amdgcn_global_load_lds((const __attribute__((address_space(1))) void*)(ksrc + ((size_t)(t) * 64 + c * 32) * INNER_), \
            (__attribute__((address_space(3))) void*)(&sK[bb][(c * 4 + wid) * SEGE]), 16, 0, 0); \
        __builtin_amdgcn_global_load_lds((const __attribute__((address_space(1))) void*)(vsrc + (size_t)(c) * 32 * J_ + (t) * 64), \
            (__attribute__((address_space(3))) void*)(&sV[bb][(c * 4 + wid) * SEGE]), 16, 0, 0); \
    } } while (0)

    STAGE_T(0, 0);
    __syncthreads();

    for (int t = 0; t < J_ / 64; ++t) {
        const int bb = t & 1;
        if (t < J_ / 64 - 1) STAGE_T(bb ^ 1, t + 1);

        const __bf16* Ks = sK[bb];
        const __bf16* Vs = sV[bb];

#pragma unroll
        for (int jsub = 0; jsub < 2; ++jsub) {
            // K fragment rows j = jsub*32 + lq ; seg addressing
            bf16x8 kf[4], vf[2][2];
            const int ksg = (jsub * 4 + (lq >> 3)) * SEGE + (lq & 7) * 64;
#pragma unroll
            for (int kc = 0; kc < 4; ++kc)
                kf[kc] = *(const bf16x8*)&Ks[ksg + (((kc * 2 + hi) ^ (lq & 7)) * 8)];
#pragma unroll
            for (int dt = 0; dt < 2; ++dt) {
                const int vsg = (dt * 4 + (lq >> 3)) * SEGE + (lq & 7) * 64;
#pragma unroll
                for (int k2 = 0; k2 < 2; ++k2)
                    vf[dt][k2] = *(const bf16x8*)&Vs[vsg + ((((jsub * 2 + k2) * 2 + hi) ^ (lq & 7)) * 8)];
            }

            // S^T[j][q] for 32 j-rows: lane col q = lq, rows j = (r&3)+8*(r>>2)+4*hi
            f32x16 s = {};
            __builtin_amdgcn_s_setprio(1);
#pragma unroll
            for (int kc = 0; kc < 4; ++kc)
                s = __builtin_amdgcn_mfma_f32_32x32x16_bf16(kf[kc], qf[kc], s, 0, 0, 0);
            __builtin_amdgcn_s_setprio(0);

            float p[16];
#pragma unroll
            for (int r = 0; r < 16; ++r)
                p[r] = __builtin_amdgcn_exp2f(s[r]);  // raw v_exp_f32; scale*log2e folded into Wq
            // pairwise tree sum (fp order fixed; log-depth dep chain)
            {
                float t0 = (p[0] + p[1]) + (p[2] + p[3]);
                float t1 = (p[4] + p[5]) + (p[6] + p[7]);
                float t2 = (p[8] + p[9]) + (p[10] + p[11]);
                float t3 = (p[12] + p[13]) + (p[14] + p[15]);
                lsum += (t0 + t1) + (t2 + t3);
            }

            // P^T fragments: B-operand slot (hi,e) of k-slot (jsub*2+k2) holds
            // P[j_local = jsub*32 + k2*16 + hi*8 + e][q]. Exchange halves via lane^32.
#pragma unroll
            for (int k2 = 0; k2 < 2; ++k2) {
                unsigned a0 = pack2(p[k2 * 8 + 0], p[k2 * 8 + 1]);   // rows {0,1}+4*hi
                unsigned a1 = pack2(p[k2 * 8 + 2], p[k2 * 8 + 3]);   // rows {2,3}+4*hi
                unsigned b0 = pack2(p[k2 * 8 + 4], p[k2 * 8 + 5]);   // rows {8,9}+4*hi
                unsigned b1 = pack2(p[k2 * 8 + 6], p[k2 * 8 + 7]);   // rows {10,11}+4*hi
                unsigned sw0 = __shfl_xor(hi ? a0 : b0, 32);
                unsigned sw1 = __shfl_xor(hi ? a1 : b1, 32);
                union { unsigned u[4]; bf16x8 v; } pu;
                pu.u[0] = hi ? sw0 : a0;     // e=0,1 : j = hi*8 + {0,1}
                pu.u[1] = hi ? sw1 : a1;     // e=2,3
                pu.u[2] = hi ? b0  : sw0;    // e=4,5
                pu.u[3] = hi ? b1  : sw1;    // e=6,7
                __builtin_amdgcn_s_setprio(1);
#pragma unroll
                for (int dt = 0; dt < 2; ++dt)
                    accO[dt] = __builtin_amdgcn_mfma_f32_32x32x16_bf16(vf[dt][k2], pu.v, accO[dt], 0, 0, 0);
                __builtin_amdgcn_s_setprio(0);
            }
        }
        __syncthreads();
    }
#undef STAGE_T

    // epilogue: merge lane-pair sums once, normalize, write O (64B-line-forming 8B stores)
    {
        float lt = lsum + __shfl_xor(lsum, 32);
        float inv = 1.f / lt;
        __bf16* op = Ob + ((size_t)b * N_ + qt * 128 + wid * 32 + lq) * INNER_ + h * D_;
#pragma unroll
        for (int dt = 0; dt < 2; ++dt)
#pragma unroll
            for (int g = 0; g < 4; ++g) {           // d = dt*32 + g*8 + hi*4 + e
                bf16x4 v4;
#pragma unroll
                for (int e = 0; e < 4; ++e) v4[e] = to_bf16(accO[dt][g * 4 + e] * inv);
                *(bf16x4*)&op[dt * 32 + g * 8 + hi * 4] = v4;
            }
    }
}

// ---------------- host ----------------
extern "C" void kernel_launch(void* const* d_in, const int* in_sizes, int n_in,
                              void* d_out, int out_size, void* d_ws, size_t ws_size,
                              hipStream_t stream)
{
    const float* x   = (const float*)d_in[0];
    const float* ctx = (const float*)d_in[1];
    const float* Wq  = (const float*)d_in[2];
    const float* Wk  = (const float*)d_in[3];
    const float* Wv  = (const float*)d_in[4];
    const float* Wo  = (const float*)d_in[5];
    const float* bo  = (const float*)d_in[6];
    float* out = (float*)d_out;

    char* w = (char*)d_ws;
    auto take = [&](size_t bytes) { char* p = w; w += bytes; return p; };
    __bf16* xb  = (__bf16*)take((size_t)B_ * N_ * QD_ * 2);      // 33.5 MB
    __bf16* cb  = (__bf16*)take((size_t)B_ * J_ * CD_ * 2);      // 12.6 MB
    __bf16* wqt = (__bf16*)take((size_t)QD_ * INNER_ * 2);
    __bf16* wkt = (__bf16*)take((size_t)CD_ * INNER_ * 2);       // wkt+wvt adjacent:
    __bf16* wvt = (__bf16*)take((size_t)CD_ * INNER_ * 2);       //  fused KV B operand
    __bf16* wot = (__bf16*)take((size_t)INNER_ * QD_ * 2);
    __bf16* Qb  = (__bf16*)take((size_t)B_ * N_ * INNER_ * 2);   // 33.5 MB
    __bf16* Kb  = (__bf16*)take((size_t)B_ * J_ * INNER_ * 2);   // 16.8 MB
    __bf16* Vt  = (__bf16*)take((size_t)B_ * J_ * INNER_ * 2);   // 16.8 MB (head-split V^T)
    __bf16* Ob  = xb;  // alias: xb is dead after the Q projection

    const float SCALE_Q = 0.125f * 1.44269504088896f;  // D^-0.5 * log2(e), folded into Wq

    cvt_bf16_k<<<(B_ * N_ * QD_) / 1024, 256, 0, stream>>>(x,   xb, (B_ * N_ * QD_) / 4);
    cvt_bf16_k<<<(B_ * J_ * CD_) / 1024, 256, 0, stream>>>(ctx, cb, (B_ * J_ * CD_) / 4);

    transpose_bf16<<<dim3(INNER_ / 32, QD_ / 32), 256, 0, stream>>>(Wq, wqt, QD_, INNER_, SCALE_Q);
    transpose_bf16<<<dim3(INNER_ / 32, CD_ / 32), 256, 0, stream>>>(Wk, wkt, CD_, INNER_, 1.f);
    transpose_bf16<<<dim3(INNER_ / 32, CD_ / 32), 256, 0, stream>>>(Wv, wvt, CD_, INNER_, 1.f);
    transpose_bf16<<<dim3(QD_ / 32, INNER_ / 32), 256, 0, stream>>>(Wo, wot, INNER_, QD_, 1.f);

    // Q proj: M=16384, N=1024 -> 128x8 tiles = 1024 blocks
    gemm_bt<0><<<1024, 256, 0, stream>>>(xb, wqt, Qb, nullptr, nullptr, nullptr, B_ * N_, INNER_, QD_);
    // fused K+V proj: M=8192, N=2048 (wkt||wvt) -> 64x16 tiles = 1024 blocks
    gemm_bt<3><<<1024, 256, 0, stream>>>(cb, wkt, Kb, Vt, nullptr, nullptr, B_ * J_, 2 * INNER_, CD_);

    attn2<<<(N_ / 128) * H_ * B_, 256, 0, stream>>>(Qb, Kb, Vt, Ob);

    // O proj: M=16384, N=1024 -> 1024 blocks, fp32 + bias epilogue
    gemm_bt<1><<<1024, 256, 0, stream>>>(Ob, wot, nullptr, nullptr, out, bo, B_ * N_, QD_, INNER_);
}

// Round 10
// 266.539 us; speedup vs baseline: 1.3438x; 1.0890x over previous
//
#include <hip/hip_runtime.h>

#define B_     8
#define N_     2048
#define J_     1024
#define QD_    1024
#define CD_    768
#define H_     16
#define D_     64
#define INNER_ 1024

typedef __attribute__((ext_vector_type(8)))  __bf16 bf16x8;
typedef __attribute__((ext_vector_type(4)))  __bf16 bf16x4;
typedef __attribute__((ext_vector_type(4)))  float  f32x4;
typedef __attribute__((ext_vector_type(16))) float  f32x16;

__device__ __forceinline__ __bf16 to_bf16(float f) { return (__bf16)f; }

__device__ __forceinline__ unsigned pack2(float lo, float hi) {
    union { __bf16 h; unsigned short u; } a, b;
    a.h = (__bf16)lo; b.h = (__bf16)hi;
    return (unsigned)a.u | ((unsigned)b.u << 16);
}

// ---------------- fp32 -> bf16 elementwise convert (vectorized) ----------------
__global__ __launch_bounds__(256)
void cvt_bf16_k(const float* __restrict__ s, __bf16* __restrict__ d, int n4)
{
    int i = blockIdx.x * 256 + threadIdx.x;
    if (i >= n4) return;
    float4 v = ((const float4*)s)[i];
    bf16x4 o;
    o[0] = (__bf16)v.x; o[1] = (__bf16)v.y; o[2] = (__bf16)v.z; o[3] = (__bf16)v.w;
    ((bf16x4*)d)[i] = o;
}

// ---------------- W[K][N] fp32 -> Wt[N][K] bf16 (LDS tile transpose, w/ scale) ----------------
__global__ __launch_bounds__(256)
void transpose_bf16(const float* __restrict__ W, __bf16* __restrict__ Wt, int K, int N, float scale)
{
    __shared__ float tile[32][33];
    const int n0 = blockIdx.x * 32;
    const int k0 = blockIdx.y * 32;
    const int tx = threadIdx.x & 31;
    const int ty = threadIdx.x >> 5;
#pragma unroll
    for (int r = 0; r < 32; r += 8)
        tile[ty + r][tx] = W[(size_t)(k0 + ty + r) * N + n0 + tx];
    __syncthreads();
#pragma unroll
    for (int r = 0; r < 32; r += 8)
        Wt[(size_t)(n0 + ty + r) * K + k0 + tx] = to_bf16(tile[tx][ty + r] * scale);
}

// ================ 256x256 8-wave pipelined GEMM (m201-style, provable sync) ==========
// C[M,N] = A[M,K]*Bt[N,K]^T. BM=BN=256, BK=64, 512 threads (8 waves, 2Mx4N).
// LDS: sA[2],sB[2] each 32KB (one K-tile), subtiled [r/16][c/32] 1KB tiles with
// st_16x32 XOR swizzle (physical col-chunk = logical ^ ((r4>>3)<<4), both sides).
// Per iteration (one K-tile): 4 quadrant phases; phase p stages one 16KB half-tile
// of K-tile it+1 into the OTHER buffer (2 gload_lds/wave); counted vmcnt(2) only at
// phase 0 (guards it-1's loads, in-order completion); 2 barriers/phase.
// FINAL=0: bf16 out. FINAL=1: fp32+bias. FINAL=3: fused KV (col<1024 Kb / else Vt).
template<int FINAL, int KDIM>
__global__ __launch_bounds__(512, 2)
void gemm8(const __bf16* __restrict__ A, const __bf16* __restrict__ Bt,
           __bf16* __restrict__ Cb, __bf16* __restrict__ Cb2, float* __restrict__ Cf,
           const float* __restrict__ bias, int N)
{
    constexpr int NIT = KDIM / 64;
    __shared__ __bf16 sA[2][16384];
    __shared__ __bf16 sB[2][16384];

    const int tid = threadIdx.x;
    const int wid = tid >> 6;
    const int l   = tid & 63;
    const int lo  = l & 15, hi = (l >> 4) & 3;

    const int gn = N >> 8;
    const int m0 = ((int)blockIdx.x / gn) * 256;
    const int n0 = ((int)blockIdx.x % gn) * 256;

    const int wm  = (wid >> 2) * 128, wn = (wid & 3) * 64;
    const int wmr = (wid >> 2) * 8,   bnr = (wid & 3) * 4;   // subtile_r bases

    // staging lane geometry (2 gloads/wave/half-tile), inverse-swizzled source
    int rOff[2], cOff[2], dOff[2];
#pragma unroll
    for (int n = 0; n < 2; ++n) {
        const int s = n * 8 + wid;
        rOff[n] = (s >> 1) * 16 + (l >> 2);
        cOff[n] = (s & 1) * 32 + (((l & 3) * 8) ^ (((l >> 5) & 1) * 16));
        dOff[n] = n * 4096 + wid * 512;                      // + (h&1)*8192
    }

    // swizzled read inner offset (elems within 512-elem subtile)
    const int inner = lo * 32 + ((hi * 8) ^ ((lo >> 3) * 16));

    f32x4 acc[8][4] = {};
    bf16x8 af[4][2], bfr[4][2];

#define STAGE8(nb, h, kt) do { \
    _Pragma("unroll") \
    for (int n = 0; n < 2; ++n) { \
        const __bf16* gp = ((h) < 2 ? A + (size_t)(m0 + ((h) & 1) * 128 + rOff[n]) * KDIM \
                                    : Bt + (size_t)(n0 + ((h) & 1) * 128 + rOff[n]) * KDIM) \
                           + (kt) + cOff[n]; \
        __bf16* dp = ((h) < 2 ? &sA[nb][((h) & 1) * 8192 + dOff[n]] \
                              : &sB[nb][((h) & 1) * 8192 + dOff[n]]); \
        __builtin_amdgcn_global_load_lds((const __attribute__((address_space(1))) void*)gp, \
                                         (__attribute__((address_space(3))) void*)dp, 16, 0, 0); \
    } } while (0)

#define RD_A(x0, cnt, nb) do { \
    _Pragma("unroll") \
    for (int x = 0; x < (cnt); ++x) \
        _Pragma("unroll") \
        for (int kk = 0; kk < 2; ++kk) \
            af[x][kk] = *(const bf16x8*)&sA[nb][((wmr + (x0) + x) * 2 + kk) * 512 + inner]; \
    } while (0)

#define RD_B(j0, cnt, nb) do { \
    _Pragma("unroll") \
    for (int j = 0; j < (cnt); ++j) \
        _Pragma("unroll") \
        for (int kk = 0; kk < 2; ++kk) \
            bfr[(j0) + j][kk] = *(const bf16x8*)&sB[nb][((bnr + (j0) + j) * 2 + kk) * 512 + inner]; \
    } while (0)

#define MMQ(mh, nh) do { \
    __builtin_amdgcn_s_setprio(1); \
    _Pragma("unroll") \
    for (int x = 0; x < 4; ++x) \
        _Pragma("unroll") \
        for (int j = 0; j < 2; ++j) \
            _Pragma("unroll") \
            for (int kk = 0; kk < 2; ++kk) \
                acc[(mh) * 4 + x][(nh) * 2 + j] = __builtin_amdgcn_mfma_f32_16x16x32_bf16( \
                    af[x][kk], bfr[(nh) * 2 + j][kk], acc[(mh) * 4 + x][(nh) * 2 + j], 0, 0, 0); \
    __builtin_amdgcn_s_setprio(0); \
    } while (0)

#define BARR() do { __builtin_amdgcn_s_barrier(); \
    asm volatile("" ::: "memory"); __builtin_amdgcn_sched_barrier(0); } while (0)

    // prologue: stage K-tile 0 into buf 0 (8 gloads/wave)
#pragma unroll
    for (int h = 0; h < 4; ++h) STAGE8(0, h, 0);

    for (int it = 0; it < NIT; ++it) {
        const int nb = it & 1, nbn = nb ^ 1;
        const int ktn = (it + 1) * 64;
        const bool notlast = (it < NIT - 1);

        // phase 0: quadrant (0,0)
        if (notlast) STAGE8(nbn, 0, ktn);
        if (notlast) asm volatile("s_waitcnt vmcnt(2)" ::: "memory");
        else         asm volatile("s_waitcnt vmcnt(0)" ::: "memory");
        BARR();
        RD_A(0, 4, nb); RD_B(0, 2, nb);
        MMQ(0, 0);
        BARR();
        // phase 1: quadrant (0,1)
        if (notlast) STAGE8(nbn, 1, ktn);
        BARR();
        RD_B(2, 2, nb);
        MMQ(0, 1);
        BARR();
        // phase 2: quadrant (1,0)
        if (notlast) STAGE8(nbn, 2, ktn);
        BARR();
        RD_A(4, 4, nb);
        MMQ(1, 0);
        BARR();
        // phase 3: quadrant (1,1)
        if (notlast) STAGE8(nbn, 3, ktn);
        BARR();
        MMQ(1, 1);
        BARR();
    }
#undef STAGE8
#undef RD_A
#undef RD_B
#undef MMQ
#undef BARR

    // epilogue (identical math to verified R9 kernels)
#pragma unroll
    for (int i = 0; i < 8; ++i) {
        const int row = m0 + wm + i * 16 + hi * 4;
#pragma unroll
        for (int j = 0; j < 4; ++j) {
            const int col = n0 + wn + j * 16 + lo;
            if (FINAL == 3) {
                if (col < 1024) {
#pragma unroll
                    for (int r = 0; r < 4; ++r)
                        Cb[(size_t)(row + r) * 1024 + col] = to_bf16(acc[i][j][r]);
                } else {
                    const int c2 = col - 1024;
                    const int head = c2 >> 6, d = c2 & 63;
                    const int bb = row >> 10, jj = row & 1023;
                    bf16x4 v4;
#pragma unroll
                    for (int r = 0; r < 4; ++r) v4[r] = to_bf16(acc[i][j][r]);
                    *(bf16x4*)&Cb2[(((size_t)(bb * 16 + head)) * 64 + d) * (size_t)J_ + jj] = v4;
                }
            } else {
#pragma unroll
                for (int r = 0; r < 4; ++r) {
                    if (FINAL == 1) Cf[(size_t)(row + r) * N + col] = acc[i][j][r] + bias[col];
                    else            Cb[(size_t)(row + r) * N + col] = to_bf16(acc[i][j][r]);
                }
            }
        }
    }
}

// ---------------- attention (unchanged from R7/R9 — 109 us) ----------------
#define SEGE 544

__global__ __launch_bounds__(256, 3)
void attn2(const __bf16* __restrict__ Qb, const __bf16* __restrict__ Kb,
           const __bf16* __restrict__ Vt, __bf16* __restrict__ Ob)
{
    __shared__ __bf16 sK[2][8 * SEGE];
    __shared__ __bf16 sV[2][8 * SEGE];

    const int tid = threadIdx.x;
    const int wid = tid >> 6;
    const int l   = tid & 63;
    const int lq  = l & 31;
    const int hi  = l >> 5;

    const int blk  = blockIdx.x;
    const int work = (blk & 7) * 256 + (blk >> 3);
    const int qt = work & 15;
    const int h  = (work >> 4) & 15;
    const int b  = work >> 8;
    const int bh = b * H_ + h;

    bf16x8 qf[4];
    {
        const __bf16* qp = Qb + ((size_t)b * N_ + qt * 128 + wid * 32 + lq) * INNER_ + h * D_;
#pragma unroll
        for (int kc = 0; kc < 4; ++kc)
            qf[kc] = *(const bf16x8*)(qp + kc * 16 + hi * 8);
    }

    f32x16 accO[2] = {};
    float lsum = 0.f;

    const int srow = l >> 3, schk = l & 7;
    const __bf16* ksrc = Kb + ((size_t)b * J_ + wid * 8 + srow) * INNER_ + h * D_ + ((schk ^ srow) * 8);
    const __bf16* vsrc = Vt + ((size_t)bh * D_ + wid * 8 + srow) * J_ + ((schk ^ srow) * 8);

#define STAGE_T(bb, t) do { \
    _Pragma("unroll") \
    for (int c = 0; c < 2; ++c) { \
        __builtin_amdgcn_global_load_lds((const __attribute__((address_space(1))) void*)(ksrc + ((size_t)(t) * 64 + c * 32) * INNER_), \
            (__attribute__((address_space(3))) void*)(&sK[bb][(c * 4 + wid) * SEGE]), 16, 0, 0); \
        __builtin_amdgcn_global_load_lds((const __attribute__((address_space(1))) void*)(vsrc + (size_t)(c) * 32 * J_ + (t) * 64), \
            (__attribute__((address_space(3))) void*)(&sV[bb][(c * 4 + wid) * SEGE]), 16, 0, 0); \
    } } while (0)

    STAGE_T(0, 0);
    __syncthreads();

    for (int t = 0; t < J_ / 64; ++t) {
        const int bb = t & 1;
        if (t < J_ / 64 - 1) STAGE_T(bb ^ 1, t + 1);

        const __bf16* Ks = sK[bb];
        const __bf16* Vs = sV[bb];

#pragma unroll
        for (int jsub = 0; jsub < 2; ++jsub) {
            bf16x8 kf[4], vf[2][2];
            const int ksg = (jsub * 4 + (lq >> 3)) * SEGE + (lq & 7) * 64;
#pragma unroll
            for (int kc = 0; kc < 4; ++kc)
                kf[kc] = *(const bf16x8*)&Ks[ksg + (((kc * 2 + hi) ^ (lq & 7)) * 8)];
#pragma unroll
            for (int dt = 0; dt < 2; ++dt) {
                const int vsg = (dt * 4 + (lq >> 3)) * SEGE + (lq & 7) * 64;
#pragma unroll
                for (int k2 = 0; k2 < 2; ++k2)
                    vf[dt][k2] = *(const bf16x8*)&Vs[vsg + ((((jsub * 2 + k2) * 2 + hi) ^ (lq & 7)) * 8)];
            }

            f32x16 s = {};
            __builtin_amdgcn_s_setprio(1);
#pragma unroll
            for (int kc = 0; kc < 4; ++kc)
                s = __builtin_amdgcn_mfma_f32_32x32x16_bf16(kf[kc], qf[kc], s, 0, 0, 0);
            __builtin_amdgcn_s_setprio(0);

            float p[16];
#pragma unroll
            for (int r = 0; r < 16; ++r)
                p[r] = __builtin_amdgcn_exp2f(s[r]);
            {
                float t0 = (p[0] + p[1]) + (p[2] + p[3]);
                float t1 = (p[4] + p[5]) + (p[6] + p[7]);
                float t2 = (p[8] + p[9]) + (p[10] + p[11]);
                float t3 = (p[12] + p[13]) + (p[14] + p[15]);
                lsum += (t0 + t1) + (t2 + t3);
            }

#pragma unroll
            for (int k2 = 0; k2 < 2; ++k2) {
                unsigned a0 = pack2(p[k2 * 8 + 0], p[k2 * 8 + 1]);
                unsigned a1 = pack2(p[k2 * 8 + 2], p[k2 * 8 + 3]);
                unsigned b0 = pack2(p[k2 * 8 + 4], p[k2 * 8 + 5]);
                unsigned b1 = pack2(p[k2 * 8 + 6], p[k2 * 8 + 7]);
                unsigned sw0 = __shfl_xor(hi ? a0 : b0, 32);
                unsigned sw1 = __shfl_xor(hi ? a1 : b1, 32);
                union { unsigned u[4]; bf16x8 v; } pu;
                pu.u[0] = hi ? sw0 : a0;
                pu.u[1] = hi ? sw1 : a1;
                pu.u[2] = hi ? b0  : sw0;
                pu.u[3] = hi ? b1  : sw1;
                __builtin_amdgcn_s_setprio(1);
#pragma unroll
                for (int dt = 0; dt < 2; ++dt)
                    accO[dt] = __builtin_amdgcn_mfma_f32_32x32x16_bf16(vf[dt][k2], pu.v, accO[dt], 0, 0, 0);
                __builtin_amdgcn_s_setprio(0);
            }
        }
        __syncthreads();
    }
#undef STAGE_T

    {
        float lt = lsum + __shfl_xor(lsum, 32);
        float inv = 1.f / lt;
        __bf16* op = Ob + ((size_t)b * N_ + qt * 128 + wid * 32 + lq) * INNER_ + h * D_;
#pragma unroll
        for (int dt = 0; dt < 2; ++dt)
#pragma unroll
            for (int g = 0; g < 4; ++g) {
                bf16x4 v4;
#pragma unroll
                for (int e = 0; e < 4; ++e) v4[e] = to_bf16(accO[dt][g * 4 + e] * inv);
                *(bf16x4*)&op[dt * 32 + g * 8 + hi * 4] = v4;
            }
    }
}

// ---------------- host ----------------
extern "C" void kernel_launch(void* const* d_in, const int* in_sizes, int n_in,
                              void* d_out, int out_size, void* d_ws, size_t ws_size,
                              hipStream_t stream)
{
    const float* x   = (const float*)d_in[0];
    const float* ctx = (const float*)d_in[1];
    const float* Wq  = (const float*)d_in[2];
    const float* Wk  = (const float*)d_in[3];
    const float* Wv  = (const float*)d_in[4];
    const float* Wo  = (const float*)d_in[5];
    const float* bo  = (const float*)d_in[6];
    float* out = (float*)d_out;

    char* w = (char*)d_ws;
    auto take = [&](size_t bytes) { char* p = w; w += bytes; return p; };
    __bf16* xb  = (__bf16*)take((size_t)B_ * N_ * QD_ * 2);
    __bf16* cb  = (__bf16*)take((size_t)B_ * J_ * CD_ * 2);
    __bf16* wqt = (__bf16*)take((size_t)QD_ * INNER_ * 2);
    __bf16* wkt = (__bf16*)take((size_t)CD_ * INNER_ * 2);   // wkt+wvt adjacent
    __bf16* wvt = (__bf16*)take((size_t)CD_ * INNER_ * 2);
    __bf16* wot = (__bf16*)take((size_t)INNER_ * QD_ * 2);
    __bf16* Qb  = (__bf16*)take((size_t)B_ * N_ * INNER_ * 2);
    __bf16* Kb  = (__bf16*)take((size_t)B_ * J_ * INNER_ * 2);
    __bf16* Vt  = (__bf16*)take((size_t)B_ * J_ * INNER_ * 2);
    __bf16* Ob  = xb;

    const float SCALE_Q = 0.125f * 1.44269504088896f;

    cvt_bf16_k<<<(B_ * N_ * QD_) / 1024, 256, 0, stream>>>(x,   xb, (B_ * N_ * QD_) / 4);
    cvt_bf16_k<<<(B_ * J_ * CD_) / 1024, 256, 0, stream>>>(ctx, cb, (B_ * J_ * CD_) / 4);

    transpose_bf16<<<dim3(INNER_ / 32, QD_ / 32), 256, 0, stream>>>(Wq, wqt, QD_, INNER_, SCALE_Q);
    transpose_bf16<<<dim3(INNER_ / 32, CD_ / 32), 256, 0, stream>>>(Wk, wkt, CD_, INNER_, 1.f);
    transpose_bf16<<<dim3(INNER_ / 32, CD_ / 32), 256, 0, stream>>>(Wv, wvt, CD_, INNER_, 1.f);
    transpose_bf16<<<dim3(QD_ / 32, INNER_ / 32), 256, 0, stream>>>(Wo, wot, INNER_, QD_, 1.f);

    // Q proj: 64 m-tiles x 4 n-tiles = 256 blocks (1/CU)
    gemm8<0, QD_><<<256, 512, 0, stream>>>(xb, wqt, Qb, nullptr, nullptr, nullptr, INNER_);
    // fused K+V proj: 32 x 8 = 256 blocks
    gemm8<3, CD_><<<256, 512, 0, stream>>>(cb, wkt, Kb, Vt, nullptr, nullptr, 2 * INNER_);

    attn2<<<(N_ / 128) * H_ * B_, 256, 0, stream>>>(Qb, Kb, Vt, Ob);

    // O proj: 64 x 4 = 256 blocks, fp32 + bias
    gemm8<1, INNER_><<<256, 512, 0, stream>>>(Ob, wot, nullptr, nullptr, out, bo, QD_);
}

// Round 11
// 261.222 us; speedup vs baseline: 1.3712x; 1.0204x over previous
//
#include <hip/hip_runtime.h>

#define B_     8
#define N_     2048
#define J_     1024
#define QD_    1024
#define CD_    768
#define H_     16
#define D_     64
#define INNER_ 1024

typedef __attribute__((ext_vector_type(8)))  __bf16 bf16x8;
typedef __attribute__((ext_vector_type(4)))  __bf16 bf16x4;
typedef __attribute__((ext_vector_type(4)))  float  f32x4;
typedef __attribute__((ext_vector_type(16))) float  f32x16;
typedef __attribute__((ext_vector_type(2)))  unsigned uint2v;

__device__ __forceinline__ __bf16 to_bf16(float f) { return (__bf16)f; }

__device__ __forceinline__ unsigned pack2(float lo, float hi) {
    union { __bf16 h; unsigned short u; } a, b;
    a.h = (__bf16)lo; b.h = (__bf16)hi;
    return (unsigned)a.u | ((unsigned)b.u << 16);
}

// ---------------- fp32 -> bf16 elementwise convert (vectorized) ----------------
__global__ __launch_bounds__(256)
void cvt_bf16_k(const float* __restrict__ s, __bf16* __restrict__ d, int n4)
{
    int i = blockIdx.x * 256 + threadIdx.x;
    if (i >= n4) return;
    float4 v = ((const float4*)s)[i];
    bf16x4 o;
    o[0] = (__bf16)v.x; o[1] = (__bf16)v.y; o[2] = (__bf16)v.z; o[3] = (__bf16)v.w;
    ((bf16x4*)d)[i] = o;
}

// ---------------- W[K][N] fp32 -> Wt[N][K] bf16 (LDS tile transpose, w/ scale) ----------------
__global__ __launch_bounds__(256)
void transpose_bf16(const float* __restrict__ W, __bf16* __restrict__ Wt, int K, int N, float scale)
{
    __shared__ float tile[32][33];
    const int n0 = blockIdx.x * 32;
    const int k0 = blockIdx.y * 32;
    const int tx = threadIdx.x & 31;
    const int ty = threadIdx.x >> 5;
#pragma unroll
    for (int r = 0; r < 32; r += 8)
        tile[ty + r][tx] = W[(size_t)(k0 + ty + r) * N + n0 + tx];
    __syncthreads();
#pragma unroll
    for (int r = 0; r < 32; r += 8)
        Wt[(size_t)(n0 + ty + r) * K + k0 + tx] = to_bf16(tile[tx][ty + r] * scale);
}

// ================ 256x256 8-wave pipelined GEMM (unchanged from R10) ==========
template<int FINAL, int KDIM>
__global__ __launch_bounds__(512, 2)
void gemm8(const __bf16* __restrict__ A, const __bf16* __restrict__ Bt,
           __bf16* __restrict__ Cb, __bf16* __restrict__ Cb2, float* __restrict__ Cf,
           const float* __restrict__ bias, int N)
{
    constexpr int NIT = KDIM / 64;
    __shared__ __bf16 sA[2][16384];
    __shared__ __bf16 sB[2][16384];

    const int tid = threadIdx.x;
    const int wid = tid >> 6;
    const int l   = tid & 63;
    const int lo  = l & 15, hi = (l >> 4) & 3;

    const int gn = N >> 8;
    const int m0 = ((int)blockIdx.x / gn) * 256;
    const int n0 = ((int)blockIdx.x % gn) * 256;

    const int wm  = (wid >> 2) * 128, wn = (wid & 3) * 64;
    const int wmr = (wid >> 2) * 8,   bnr = (wid & 3) * 4;

    int rOff[2], cOff[2], dOff[2];
#pragma unroll
    for (int n = 0; n < 2; ++n) {
        const int s = n * 8 + wid;
        rOff[n] = (s >> 1) * 16 + (l >> 2);
        cOff[n] = (s & 1) * 32 + (((l & 3) * 8) ^ (((l >> 5) & 1) * 16));
        dOff[n] = n * 4096 + wid * 512;
    }

    const int inner = lo * 32 + ((hi * 8) ^ ((lo >> 3) * 16));

    f32x4 acc[8][4] = {};
    bf16x8 af[4][2], bfr[4][2];

#define STAGE8(nb, h, kt) do { \
    _Pragma("unroll") \
    for (int n = 0; n < 2; ++n) { \
        const __bf16* gp = ((h) < 2 ? A + (size_t)(m0 + ((h) & 1) * 128 + rOff[n]) * KDIM \
                                    : Bt + (size_t)(n0 + ((h) & 1) * 128 + rOff[n]) * KDIM) \
                           + (kt) + cOff[n]; \
        __bf16* dp = ((h) < 2 ? &sA[nb][((h) & 1) * 8192 + dOff[n]] \
                              : &sB[nb][((h) & 1) * 8192 + dOff[n]]); \
        __builtin_amdgcn_global_load_lds((const __attribute__((address_space(1))) void*)gp, \
                                         (__attribute__((address_space(3))) void*)dp, 16, 0, 0); \
    } } while (0)

#define RD_A(x0, cnt, nb) do { \
    _Pragma("unroll") \
    for (int x = 0; x < (cnt); ++x) \
        _Pragma("unroll") \
        for (int kk = 0; kk < 2; ++kk) \
            af[x][kk] = *(const bf16x8*)&sA[nb][((wmr + (x0) + x) * 2 + kk) * 512 + inner]; \
    } while (0)

#define RD_B(j0, cnt, nb) do { \
    _Pragma("unroll") \
    for (int j = 0; j < (cnt); ++j) \
        _Pragma("unroll") \
        for (int kk = 0; kk < 2; ++kk) \
            bfr[(j0) + j][kk] = *(const bf16x8*)&sB[nb][((bnr + (j0) + j) * 2 + kk) * 512 + inner]; \
    } while (0)

#define MMQ(mh, nh) do { \
    __builtin_amdgcn_s_setprio(1); \
    _Pragma("unroll") \
    for (int x = 0; x < 4; ++x) \
        _Pragma("unroll") \
        for (int j = 0; j < 2; ++j) \
            _Pragma("unroll") \
            for (int kk = 0; kk < 2; ++kk) \
                acc[(mh) * 4 + x][(nh) * 2 + j] = __builtin_amdgcn_mfma_f32_16x16x32_bf16( \
                    af[x][kk], bfr[(nh) * 2 + j][kk], acc[(mh) * 4 + x][(nh) * 2 + j], 0, 0, 0); \
    __builtin_amdgcn_s_setprio(0); \
    } while (0)

#define BARR() do { __builtin_amdgcn_s_barrier(); \
    asm volatile("" ::: "memory"); __builtin_amdgcn_sched_barrier(0); } while (0)

#pragma unroll
    for (int h = 0; h < 4; ++h) STAGE8(0, h, 0);

    for (int it = 0; it < NIT; ++it) {
        const int nb = it & 1, nbn = nb ^ 1;
        const int ktn = (it + 1) * 64;
        const bool notlast = (it < NIT - 1);

        if (notlast) STAGE8(nbn, 0, ktn);
        if (notlast) asm volatile("s_waitcnt vmcnt(2)" ::: "memory");
        else         asm volatile("s_waitcnt vmcnt(0)" ::: "memory");
        BARR();
        RD_A(0, 4, nb); RD_B(0, 2, nb);
        MMQ(0, 0);
        BARR();
        if (notlast) STAGE8(nbn, 1, ktn);
        BARR();
        RD_B(2, 2, nb);
        MMQ(0, 1);
        BARR();
        if (notlast) STAGE8(nbn, 2, ktn);
        BARR();
        RD_A(4, 4, nb);
        MMQ(1, 0);
        BARR();
        if (notlast) STAGE8(nbn, 3, ktn);
        BARR();
        MMQ(1, 1);
        BARR();
    }
#undef STAGE8
#undef RD_A
#undef RD_B
#undef MMQ
#undef BARR

#pragma unroll
    for (int i = 0; i < 8; ++i) {
        const int row = m0 + wm + i * 16 + hi * 4;
#pragma unroll
        for (int j = 0; j < 4; ++j) {
            const int col = n0 + wn + j * 16 + lo;
            if (FINAL == 3) {
                if (col < 1024) {
#pragma unroll
                    for (int r = 0; r < 4; ++r)
                        Cb[(size_t)(row + r) * 1024 + col] = to_bf16(acc[i][j][r]);
                } else {
                    const int c2 = col - 1024;
                    const int head = c2 >> 6, d = c2 & 63;
                    const int bb = row >> 10, jj = row & 1023;
                    bf16x4 v4;
#pragma unroll
                    for (int r = 0; r < 4; ++r) v4[r] = to_bf16(acc[i][j][r]);
                    *(bf16x4*)&Cb2[(((size_t)(bb * 16 + head)) * 64 + d) * (size_t)J_ + jj] = v4;
                }
            } else {
#pragma unroll
                for (int r = 0; r < 4; ++r) {
                    if (FINAL == 1) Cf[(size_t)(row + r) * N + col] = acc[i][j][r] + bias[col];
                    else            Cb[(size_t)(row + r) * N + col] = to_bf16(acc[i][j][r]);
                }
            }
        }
    }
}

// ---------------- attention: R10 structure, shfl_xor -> permlane32_swap ----------------
// swap(a,b) returns {a_row0||b_row0, a_row1||b_row1}; with a=pack(own j lo-rows),
// b=pack(own j hi-rows) these are exactly B-operand dwords u[0] and u[2] for BOTH
// halves — replaces 2 ds_bpermute (32 conflict-cyc each) + 6 cndmask with 2 VALU ops.
#define SEGE 544

__global__ __launch_bounds__(256, 3)
void attn2(const __bf16* __restrict__ Qb, const __bf16* __restrict__ Kb,
           const __bf16* __restrict__ Vt, __bf16* __restrict__ Ob)
{
    __shared__ __bf16 sK[2][8 * SEGE];
    __shared__ __bf16 sV[2][8 * SEGE];

    const int tid = threadIdx.x;
    const int wid = tid >> 6;
    const int l   = tid & 63;
    const int lq  = l & 31;
    const int hi  = l >> 5;

    const int blk  = blockIdx.x;
    const int work = (blk & 7) * 256 + (blk >> 3);
    const int qt = work & 15;
    const int h  = (work >> 4) & 15;
    const int b  = work >> 8;
    const int bh = b * H_ + h;

    bf16x8 qf[4];
    {
        const __bf16* qp = Qb + ((size_t)b * N_ + qt * 128 + wid * 32 + lq) * INNER_ + h * D_;
#pragma unroll
        for (int kc = 0; kc < 4; ++kc)
            qf[kc] = *(const bf16x8*)(qp + kc * 16 + hi * 8);
    }

    f32x16 accO[2] = {};
    float lsum = 0.f;

    const int srow = l >> 3, schk = l & 7;
    const __bf16* ksrc = Kb + ((size_t)b * J_ + wid * 8 + srow) * INNER_ + h * D_ + ((schk ^ srow) * 8);
    const __bf16* vsrc = Vt + ((size_t)bh * D_ + wid * 8 + srow) * J_ + ((schk ^ srow) * 8);

#define STAGE_T(bb, t) do { \
    _Pragma("unroll") \
    for (int c = 0; c < 2; ++c) { \
        __builtin_amdgcn_global_load_lds((const __attribute__((address_space(1))) void*)(ksrc + ((size_t)(t) * 64 + c * 32) * INNER_), \
            (__attribute__((address_space(3))) void*)(&sK[bb][(c * 4 + wid) * SEGE]), 16, 0, 0); \
        __builtin_amdgcn_global_load_lds((const __attribute__((address_space(1))) void*)(vsrc + (size_t)(c) * 32 * J_ + (t) * 64), \
            (__attribute__((address_space(3))) void*)(&sV[bb][(c * 4 + wid) * SEGE]), 16, 0, 0); \
    } } while (0)

    STAGE_T(0, 0);
    __syncthreads();

    for (int t = 0; t < J_ / 64; ++t) {
        const int bb = t & 1;
        if (t < J_ / 64 - 1) STAGE_T(bb ^ 1, t + 1);

        const __bf16* Ks = sK[bb];
        const __bf16* Vs = sV[bb];

#pragma unroll
        for (int jsub = 0; jsub < 2; ++jsub) {
            bf16x8 kf[4], vf[2][2];
            const int ksg = (jsub * 4 + (lq >> 3)) * SEGE + (lq & 7) * 64;
#pragma unroll
            for (int kc = 0; kc < 4; ++kc)
                kf[kc] = *(const bf16x8*)&Ks[ksg + (((kc * 2 + hi) ^ (lq & 7)) * 8)];
#pragma unroll
            for (int dt = 0; dt < 2; ++dt) {
                const int vsg = (dt * 4 + (lq >> 3)) * SEGE + (lq & 7) * 64;
#pragma unroll
                for (int k2 = 0; k2 < 2; ++k2)
                    vf[dt][k2] = *(const bf16x8*)&Vs[vsg + ((((jsub * 2 + k2) * 2 + hi) ^ (lq & 7)) * 8)];
            }

            f32x16 s = {};
            __builtin_amdgcn_s_setprio(1);
#pragma unroll
            for (int kc = 0; kc < 4; ++kc)
                s = __builtin_amdgcn_mfma_f32_32x32x16_bf16(kf[kc], qf[kc], s, 0, 0, 0);
            __builtin_amdgcn_s_setprio(0);

            float p[16];
#pragma unroll
            for (int r = 0; r < 16; ++r)
                p[r] = __builtin_amdgcn_exp2f(s[r]);
            {
                float t0 = (p[0] + p[1]) + (p[2] + p[3]);
                float t1 = (p[4] + p[5]) + (p[6] + p[7]);
                float t2 = (p[8] + p[9]) + (p[10] + p[11]);
                float t3 = (p[12] + p[13]) + (p[14] + p[15]);
                lsum += (t0 + t1) + (t2 + t3);
            }

#pragma unroll
            for (int k2 = 0; k2 < 2; ++k2) {
                unsigned a0 = pack2(p[k2 * 8 + 0], p[k2 * 8 + 1]);   // own j rows {0,1}+4*hi
                unsigned a1 = pack2(p[k2 * 8 + 2], p[k2 * 8 + 3]);   // own j rows {2,3}+4*hi
                unsigned b0 = pack2(p[k2 * 8 + 4], p[k2 * 8 + 5]);   // own j rows {8,9}+4*hi
                unsigned b1 = pack2(p[k2 * 8 + 6], p[k2 * 8 + 7]);   // own j rows {10,11}+4*hi
                uint2v r0 = __builtin_amdgcn_permlane32_swap(a0, b0, false, false);
                uint2v r1 = __builtin_amdgcn_permlane32_swap(a1, b1, false, false);
                union { unsigned u[4]; bf16x8 v; } pu;
                pu.u[0] = r0[0];   // lanes<32: a0 own | lanes>=32: b0 from lane-32
                pu.u[1] = r1[0];
                pu.u[2] = r0[1];   // lanes<32: a0 from lane+32 | lanes>=32: b0 own
                pu.u[3] = r1[1];
                __builtin_amdgcn_s_setprio(1);
#pragma unroll
                for (int dt = 0; dt < 2; ++dt)
                    accO[dt] = __builtin_amdgcn_mfma_f32_32x32x16_bf16(vf[dt][k2], pu.v, accO[dt], 0, 0, 0);
                __builtin_amdgcn_s_setprio(0);
            }
        }
        __syncthreads();
    }
#undef STAGE_T

    {
        float lt = lsum + __shfl_xor(lsum, 32);
        float inv = 1.f / lt;
        __bf16* op = Ob + ((size_t)b * N_ + qt * 128 + wid * 32 + lq) * INNER_ + h * D_;
#pragma unroll
        for (int dt = 0; dt < 2; ++dt)
#pragma unroll
            for (int g = 0; g < 4; ++g) {
                bf16x4 v4;
#pragma unroll
                for (int e = 0; e < 4; ++e) v4[e] = to_bf16(accO[dt][g * 4 + e] * inv);
                *(bf16x4*)&op[dt * 32 + g * 8 + hi * 4] = v4;
            }
    }
}

// ---------------- host ----------------
extern "C" void kernel_launch(void* const* d_in, const int* in_sizes, int n_in,
                              void* d_out, int out_size, void* d_ws, size_t ws_size,
                              hipStream_t stream)
{
    const float* x   = (const float*)d_in[0];
    const float* ctx = (const float*)d_in[1];
    const float* Wq  = (const float*)d_in[2];
    const float* Wk  = (const float*)d_in[3];
    const float* Wv  = (const float*)d_in[4];
    const float* Wo  = (const float*)d_in[5];
    const float* bo  = (const float*)d_in[6];
    float* out = (float*)d_out;

    char* w = (char*)d_ws;
    auto take = [&](size_t bytes) { char* p = w; w += bytes; return p; };
    __bf16* xb  = (__bf16*)take((size_t)B_ * N_ * QD_ * 2);
    __bf16* cb  = (__bf16*)take((size_t)B_ * J_ * CD_ * 2);
    __bf16* wqt = (__bf16*)take((size_t)QD_ * INNER_ * 2);
    __bf16* wkt = (__bf16*)take((size_t)CD_ * INNER_ * 2);   // wkt+wvt adjacent
    __bf16* wvt = (__bf16*)take((size_t)CD_ * INNER_ * 2);
    __bf16* wot = (__bf16*)take((size_t)INNER_ * QD_ * 2);
    __bf16* Qb  = (__bf16*)take((size_t)B_ * N_ * INNER_ * 2);
    __bf16* Kb  = (__bf16*)take((size_t)B_ * J_ * INNER_ * 2);
    __bf16* Vt  = (__bf16*)take((size_t)B_ * J_ * INNER_ * 2);
    __bf16* Ob  = xb;

    const float SCALE_Q = 0.125f * 1.44269504088896f;

    cvt_bf16_k<<<(B_ * N_ * QD_) / 1024, 256, 0, stream>>>(x,   xb, (B_ * N_ * QD_) / 4);
    cvt_bf16_k<<<(B_ * J_ * CD_) / 1024, 256, 0, stream>>>(ctx, cb, (B_ * J_ * CD_) / 4);

    transpose_bf16<<<dim3(INNER_ / 32, QD_ / 32), 256, 0, stream>>>(Wq, wqt, QD_, INNER_, SCALE_Q);
    transpose_bf16<<<dim3(INNER_ / 32, CD_ / 32), 256, 0, stream>>>(Wk, wkt, CD_, INNER_, 1.f);
    transpose_bf16<<<dim3(INNER_ / 32, CD_ / 32), 256, 0, stream>>>(Wv, wvt, CD_, INNER_, 1.f);
    transpose_bf16<<<dim3(QD_ / 32, INNER_ / 32), 256, 0, stream>>>(Wo, wot, INNER_, QD_, 1.f);

    gemm8<0, QD_><<<256, 512, 0, stream>>>(xb, wqt, Qb, nullptr, nullptr, nullptr, INNER_);
    gemm8<3, CD_><<<256, 512, 0, stream>>>(cb, wkt, Kb, Vt, nullptr, nullptr, 2 * INNER_);

    attn2<<<(N_ / 128) * H_ * B_, 256, 0, stream>>>(Qb, Kb, Vt, Ob);

    gemm8<1, INNER_><<<256, 512, 0, stream>>>(Ob, wot, nullptr, nullptr, out, bo, QD_);
}

// Round 12
// 257.615 us; speedup vs baseline: 1.3904x; 1.0140x over previous
//
#include <hip/hip_runtime.h>

#define B_     8
#define N_     2048
#define J_     1024
#define QD_    1024
#define CD_    768
#define H_     16
#define D_     64
#define INNER_ 1024

typedef __attribute__((ext_vector_type(8)))  __bf16 bf16x8;
typedef __attribute__((ext_vector_type(4)))  __bf16 bf16x4;
typedef __attribute__((ext_vector_type(4)))  float  f32x4;
typedef __attribute__((ext_vector_type(16))) float  f32x16;
typedef __attribute__((ext_vector_type(2)))  unsigned uint2v;

__device__ __forceinline__ __bf16 to_bf16(float f) { return (__bf16)f; }

__device__ __forceinline__ unsigned pack2(float lo, float hi) {
    union { __bf16 h; unsigned short u; } a, b;
    a.h = (__bf16)lo; b.h = (__bf16)hi;
    return (unsigned)a.u | ((unsigned)b.u << 16);
}

// ---------------- fused fp32 -> bf16 convert: x then ctx in one flat grid ----------------
__global__ __launch_bounds__(256)
void cvt_all(const float* __restrict__ x, const float* __restrict__ ctx,
             __bf16* __restrict__ xb, __bf16* __restrict__ cb)
{
    const int nx = (B_ * N_ * QD_) / 4;
    const int nc = (B_ * J_ * CD_) / 4;
    int i = blockIdx.x * 256 + threadIdx.x;
    if (i < nx) {
        float4 v = ((const float4*)x)[i];
        bf16x4 o;
        o[0] = (__bf16)v.x; o[1] = (__bf16)v.y; o[2] = (__bf16)v.z; o[3] = (__bf16)v.w;
        ((bf16x4*)xb)[i] = o;
    } else if (i < nx + nc) {
        float4 v = ((const float4*)ctx)[i - nx];
        bf16x4 o;
        o[0] = (__bf16)v.x; o[1] = (__bf16)v.y; o[2] = (__bf16)v.z; o[3] = (__bf16)v.w;
        ((bf16x4*)cb)[i - nx] = o;
    }
}

// ---------------- fused weight transposes: all 4 weights, blockIdx.z selects ----------------
__global__ __launch_bounds__(256)
void transpose_all(const float* __restrict__ Wq, const float* __restrict__ Wk,
                   const float* __restrict__ Wv, const float* __restrict__ Wo,
                   __bf16* __restrict__ wqt, __bf16* __restrict__ wkt,
                   __bf16* __restrict__ wvt, __bf16* __restrict__ wot, float sq)
{
    __shared__ float tile[32][33];
    const int z = blockIdx.z;
    const float* W;  __bf16* Wt;  int K;  float scale = 1.f;
    if (z == 0)      { W = Wq; Wt = wqt; K = QD_;   scale = sq; }
    else if (z == 1) { W = Wk; Wt = wkt; K = CD_; }
    else if (z == 2) { W = Wv; Wt = wvt; K = CD_; }
    else             { W = Wo; Wt = wot; K = INNER_; }
    const int N = 1024;                      // all outputs have N=1024 cols (INNER or QD)
    const int n0 = blockIdx.x * 32;
    const int k0 = blockIdx.y * 32;
    if (k0 >= K) return;
    const int tx = threadIdx.x & 31;
    const int ty = threadIdx.x >> 5;
#pragma unroll
    for (int r = 0; r < 32; r += 8)
        tile[ty + r][tx] = W[(size_t)(k0 + ty + r) * N + n0 + tx];
    __syncthreads();
#pragma unroll
    for (int r = 0; r < 32; r += 8)
        Wt[(size_t)(n0 + ty + r) * K + k0 + tx] = to_bf16(tile[tx][ty + r] * scale);
}

// ================ 256x256 8-wave pipelined GEMM (unchanged from R10/R11) ==========
template<int FINAL, int KDIM>
__global__ __launch_bounds__(512, 2)
void gemm8(const __bf16* __restrict__ A, const __bf16* __restrict__ Bt,
           __bf16* __restrict__ Cb, __bf16* __restrict__ Cb2, float* __restrict__ Cf,
           const float* __restrict__ bias, int N)
{
    constexpr int NIT = KDIM / 64;
    __shared__ __bf16 sA[2][16384];
    __shared__ __bf16 sB[2][16384];

    const int tid = threadIdx.x;
    const int wid = tid >> 6;
    const int l   = tid & 63;
    const int lo  = l & 15, hi = (l >> 4) & 3;

    const int gn = N >> 8;
    const int m0 = ((int)blockIdx.x / gn) * 256;
    const int n0 = ((int)blockIdx.x % gn) * 256;

    const int wm  = (wid >> 2) * 128, wn = (wid & 3) * 64;
    const int wmr = (wid >> 2) * 8,   bnr = (wid & 3) * 4;

    int rOff[2], cOff[2], dOff[2];
#pragma unroll
    for (int n = 0; n < 2; ++n) {
        const int s = n * 8 + wid;
        rOff[n] = (s >> 1) * 16 + (l >> 2);
        cOff[n] = (s & 1) * 32 + (((l & 3) * 8) ^ (((l >> 5) & 1) * 16));
        dOff[n] = n * 4096 + wid * 512;
    }

    const int inner = lo * 32 + ((hi * 8) ^ ((lo >> 3) * 16));

    f32x4 acc[8][4] = {};
    bf16x8 af[4][2], bfr[4][2];

#define STAGE8(nb, h, kt) do { \
    _Pragma("unroll") \
    for (int n = 0; n < 2; ++n) { \
        const __bf16* gp = ((h) < 2 ? A + (size_t)(m0 + ((h) & 1) * 128 + rOff[n]) * KDIM \
                                    : Bt + (size_t)(n0 + ((h) & 1) * 128 + rOff[n]) * KDIM) \
                           + (kt) + cOff[n]; \
        __bf16* dp = ((h) < 2 ? &sA[nb][((h) & 1) * 8192 + dOff[n]] \
                              : &sB[nb][((h) & 1) * 8192 + dOff[n]]); \
        __builtin_amdgcn_global_load_lds((const __attribute__((address_space(1))) void*)gp, \
                                         (__attribute__((address_space(3))) void*)dp, 16, 0, 0); \
    } } while (0)

#define RD_A(x0, cnt, nb) do { \
    _Pragma("unroll") \
    for (int x = 0; x < (cnt); ++x) \
        _Pragma("unroll") \
        for (int kk = 0; kk < 2; ++kk) \
            af[x][kk] = *(const bf16x8*)&sA[nb][((wmr + (x0) + x) * 2 + kk) * 512 + inner]; \
    } while (0)

#define RD_B(j0, cnt, nb) do { \
    _Pragma("unroll") \
    for (int j = 0; j < (cnt); ++j) \
        _Pragma("unroll") \
        for (int kk = 0; kk < 2; ++kk) \
            bfr[(j0) + j][kk] = *(const bf16x8*)&sB[nb][((bnr + (j0) + j) * 2 + kk) * 512 + inner]; \
    } while (0)

#define MMQ(mh, nh) do { \
    __builtin_amdgcn_s_setprio(1); \
    _Pragma("unroll") \
    for (int x = 0; x < 4; ++x) \
        _Pragma("unroll") \
        for (int j = 0; j < 2; ++j) \
            _Pragma("unroll") \
            for (int kk = 0; kk < 2; ++kk) \
                acc[(mh) * 4 + x][(nh) * 2 + j] = __builtin_amdgcn_mfma_f32_16x16x32_bf16( \
                    af[x][kk], bfr[(nh) * 2 + j][kk], acc[(mh) * 4 + x][(nh) * 2 + j], 0, 0, 0); \
    __builtin_amdgcn_s_setprio(0); \
    } while (0)

#define BARR() do { __builtin_amdgcn_s_barrier(); \
    asm volatile("" ::: "memory"); __builtin_amdgcn_sched_barrier(0); } while (0)

#pragma unroll
    for (int h = 0; h < 4; ++h) STAGE8(0, h, 0);

    for (int it = 0; it < NIT; ++it) {
        const int nb = it & 1, nbn = nb ^ 1;
        const int ktn = (it + 1) * 64;
        const bool notlast = (it < NIT - 1);

        if (notlast) STAGE8(nbn, 0, ktn);
        if (notlast) asm volatile("s_waitcnt vmcnt(2)" ::: "memory");
        else         asm volatile("s_waitcnt vmcnt(0)" ::: "memory");
        BARR();
        RD_A(0, 4, nb); RD_B(0, 2, nb);
        MMQ(0, 0);
        BARR();
        if (notlast) STAGE8(nbn, 1, ktn);
        BARR();
        RD_B(2, 2, nb);
        MMQ(0, 1);
        BARR();
        if (notlast) STAGE8(nbn, 2, ktn);
        BARR();
        RD_A(4, 4, nb);
        MMQ(1, 0);
        BARR();
        if (notlast) STAGE8(nbn, 3, ktn);
        BARR();
        MMQ(1, 1);
        BARR();
    }
#undef STAGE8
#undef RD_A
#undef RD_B
#undef MMQ
#undef BARR

#pragma unroll
    for (int i = 0; i < 8; ++i) {
        const int row = m0 + wm + i * 16 + hi * 4;
#pragma unroll
        for (int j = 0; j < 4; ++j) {
            const int col = n0 + wn + j * 16 + lo;
            if (FINAL == 3) {
                if (col < 1024) {
#pragma unroll
                    for (int r = 0; r < 4; ++r)
                        Cb[(size_t)(row + r) * 1024 + col] = to_bf16(acc[i][j][r]);
                } else {
                    const int c2 = col - 1024;
                    const int head = c2 >> 6, d = c2 & 63;
                    const int bb = row >> 10, jj = row & 1023;
                    bf16x4 v4;
#pragma unroll
                    for (int r = 0; r < 4; ++r) v4[r] = to_bf16(acc[i][j][r]);
                    *(bf16x4*)&Cb2[(((size_t)(bb * 16 + head)) * 64 + d) * (size_t)J_ + jj] = v4;
                }
            } else {
#pragma unroll
                for (int r = 0; r < 4; ++r) {
                    if (FINAL == 1) Cf[(size_t)(row + r) * N + col] = acc[i][j][r] + bias[col];
                    else            Cb[(size_t)(row + r) * N + col] = to_bf16(acc[i][j][r]);
                }
            }
        }
    }
}

// ---------------- attention (R11 structure; launch_bounds 3 -> 4 blocks/CU) ----------------
#define SEGE 544

__global__ __launch_bounds__(256, 4)
void attn2(const __bf16* __restrict__ Qb, const __bf16* __restrict__ Kb,
           const __bf16* __restrict__ Vt, __bf16* __restrict__ Ob)
{
    __shared__ __bf16 sK[2][8 * SEGE];
    __shared__ __bf16 sV[2][8 * SEGE];

    const int tid = threadIdx.x;
    const int wid = tid >> 6;
    const int l   = tid & 63;
    const int lq  = l & 31;
    const int hi  = l >> 5;

    const int blk  = blockIdx.x;
    const int work = (blk & 7) * 256 + (blk >> 3);
    const int qt = work & 15;
    const int h  = (work >> 4) & 15;
    const int b  = work >> 8;
    const int bh = b * H_ + h;

    bf16x8 qf[4];
    {
        const __bf16* qp = Qb + ((size_t)b * N_ + qt * 128 + wid * 32 + lq) * INNER_ + h * D_;
#pragma unroll
        for (int kc = 0; kc < 4; ++kc)
            qf[kc] = *(const bf16x8*)(qp + kc * 16 + hi * 8);
    }

    f32x16 accO[2] = {};
    float lsum = 0.f;

    const int srow = l >> 3, schk = l & 7;
    const __bf16* ksrc = Kb + ((size_t)b * J_ + wid * 8 + srow) * INNER_ + h * D_ + ((schk ^ srow) * 8);
    const __bf16* vsrc = Vt + ((size_t)bh * D_ + wid * 8 + srow) * J_ + ((schk ^ srow) * 8);

#define STAGE_T(bb, t) do { \
    _Pragma("unroll") \
    for (int c = 0; c < 2; ++c) { \
        __builtin_amdgcn_global_load_lds((const __attribute__((address_space(1))) void*)(ksrc + ((size_t)(t) * 64 + c * 32) * INNER_), \
            (__attribute__((address_space(3))) void*)(&sK[bb][(c * 4 + wid) * SEGE]), 16, 0, 0); \
        __builtin_amdgcn_global_load_lds((const __attribute__((address_space(1))) void*)(vsrc + (size_t)(c) * 32 * J_ + (t) * 64), \
            (__attribute__((address_space(3))) void*)(&sV[bb][(c * 4 + wid) * SEGE]), 16, 0, 0); \
    } } while (0)

    STAGE_T(0, 0);
    __syncthreads();

    for (int t = 0; t < J_ / 64; ++t) {
        const int bb = t & 1;
        if (t < J_ / 64 - 1) STAGE_T(bb ^ 1, t + 1);

        const __bf16* Ks = sK[bb];
        const __bf16* Vs = sV[bb];

#pragma unroll
        for (int jsub = 0; jsub < 2; ++jsub) {
            bf16x8 kf[4], vf[2][2];
            const int ksg = (jsub * 4 + (lq >> 3)) * SEGE + (lq & 7) * 64;
#pragma unroll
            for (int kc = 0; kc < 4; ++kc)
                kf[kc] = *(const bf16x8*)&Ks[ksg + (((kc * 2 + hi) ^ (lq & 7)) * 8)];
#pragma unroll
            for (int dt = 0; dt < 2; ++dt) {
                const int vsg = (dt * 4 + (lq >> 3)) * SEGE + (lq & 7) * 64;
#pragma unroll
                for (int k2 = 0; k2 < 2; ++k2)
                    vf[dt][k2] = *(const bf16x8*)&Vs[vsg + ((((jsub * 2 + k2) * 2 + hi) ^ (lq & 7)) * 8)];
            }

            f32x16 s = {};
            __builtin_amdgcn_s_setprio(1);
#pragma unroll
            for (int kc = 0; kc < 4; ++kc)
                s = __builtin_amdgcn_mfma_f32_32x32x16_bf16(kf[kc], qf[kc], s, 0, 0, 0);
            __builtin_amdgcn_s_setprio(0);

            float p[16];
#pragma unroll
            for (int r = 0; r < 16; ++r)
                p[r] = __builtin_amdgcn_exp2f(s[r]);
            {
                float t0 = (p[0] + p[1]) + (p[2] + p[3]);
                float t1 = (p[4] + p[5]) + (p[6] + p[7]);
                float t2 = (p[8] + p[9]) + (p[10] + p[11]);
                float t3 = (p[12] + p[13]) + (p[14] + p[15]);
                lsum += (t0 + t1) + (t2 + t3);
            }

#pragma unroll
            for (int k2 = 0; k2 < 2; ++k2) {
                unsigned a0 = pack2(p[k2 * 8 + 0], p[k2 * 8 + 1]);
                unsigned a1 = pack2(p[k2 * 8 + 2], p[k2 * 8 + 3]);
                unsigned b0 = pack2(p[k2 * 8 + 4], p[k2 * 8 + 5]);
                unsigned b1 = pack2(p[k2 * 8 + 6], p[k2 * 8 + 7]);
                uint2v r0 = __builtin_amdgcn_permlane32_swap(a0, b0, false, false);
                uint2v r1 = __builtin_amdgcn_permlane32_swap(a1, b1, false, false);
                union { unsigned u[4]; bf16x8 v; } pu;
                pu.u[0] = r0[0];
                pu.u[1] = r1[0];
                pu.u[2] = r0[1];
                pu.u[3] = r1[1];
                __builtin_amdgcn_s_setprio(1);
#pragma unroll
                for (int dt = 0; dt < 2; ++dt)
                    accO[dt] = __builtin_amdgcn_mfma_f32_32x32x16_bf16(vf[dt][k2], pu.v, accO[dt], 0, 0, 0);
                __builtin_amdgcn_s_setprio(0);
            }
        }
        __syncthreads();
    }
#undef STAGE_T

    {
        float lt = lsum + __shfl_xor(lsum, 32);
        float inv = 1.f / lt;
        __bf16* op = Ob + ((size_t)b * N_ + qt * 128 + wid * 32 + lq) * INNER_ + h * D_;
#pragma unroll
        for (int dt = 0; dt < 2; ++dt)
#pragma unroll
            for (int g = 0; g < 4; ++g) {
                bf16x4 v4;
#pragma unroll
                for (int e = 0; e < 4; ++e) v4[e] = to_bf16(accO[dt][g * 4 + e] * inv);
                *(bf16x4*)&op[dt * 32 + g * 8 + hi * 4] = v4;
            }
    }
}

// ---------------- host ----------------
extern "C" void kernel_launch(void* const* d_in, const int* in_sizes, int n_in,
                              void* d_out, int out_size, void* d_ws, size_t ws_size,
                              hipStream_t stream)
{
    const float* x   = (const float*)d_in[0];
    const float* ctx = (const float*)d_in[1];
    const float* Wq  = (const float*)d_in[2];
    const float* Wk  = (const float*)d_in[3];
    const float* Wv  = (const float*)d_in[4];
    const float* Wo  = (const float*)d_in[5];
    const float* bo  = (const float*)d_in[6];
    float* out = (float*)d_out;

    char* w = (char*)d_ws;
    auto take = [&](size_t bytes) { char* p = w; w += bytes; return p; };
    __bf16* xb  = (__bf16*)take((size_t)B_ * N_ * QD_ * 2);
    __bf16* cb  = (__bf16*)take((size_t)B_ * J_ * CD_ * 2);
    __bf16* wqt = (__bf16*)take((size_t)QD_ * INNER_ * 2);
    __bf16* wkt = (__bf16*)take((size_t)CD_ * INNER_ * 2);   // wkt+wvt adjacent
    __bf16* wvt = (__bf16*)take((size_t)CD_ * INNER_ * 2);
    __bf16* wot = (__bf16*)take((size_t)INNER_ * QD_ * 2);
    __bf16* Qb  = (__bf16*)take((size_t)B_ * N_ * INNER_ * 2);
    __bf16* Kb  = (__bf16*)take((size_t)B_ * J_ * INNER_ * 2);
    __bf16* Vt  = (__bf16*)take((size_t)B_ * J_ * INNER_ * 2);
    __bf16* Ob  = xb;

    const float SCALE_Q = 0.125f * 1.44269504088896f;

    const int ncvt = (B_ * N_ * QD_ + B_ * J_ * CD_) / 4;
    cvt_all<<<(ncvt + 255) / 256, 256, 0, stream>>>(x, ctx, xb, cb);
    transpose_all<<<dim3(32, 32, 4), 256, 0, stream>>>(Wq, Wk, Wv, Wo, wqt, wkt, wvt, wot, SCALE_Q);

    gemm8<0, QD_><<<256, 512, 0, stream>>>(xb, wqt, Qb, nullptr, nullptr, nullptr, INNER_);
    gemm8<3, CD_><<<256, 512, 0, stream>>>(cb, wkt, Kb, Vt, nullptr, nullptr, 2 * INNER_);

    attn2<<<(N_ / 128) * H_ * B_, 256, 0, stream>>>(Qb, Kb, Vt, Ob);

    gemm8<1, INNER_><<<256, 512, 0, stream>>>(Ob, wot, nullptr, nullptr, out, bo, QD_);
}

// Round 13
// 244.933 us; speedup vs baseline: 1.4624x; 1.0518x over previous
//
#include <hip/hip_runtime.h>

#define B_     8
#define N_     2048
#define J_     1024
#define QD_    1024
#define CD_    768
#define H_     16
#define D_     64
#define INNER_ 1024

typedef __attribute__((ext_vector_type(8)))  __bf16 bf16x8;
typedef __attribute__((ext_vector_type(4)))  __bf16 bf16x4;
typedef __attribute__((ext_vector_type(4)))  float  f32x4;
typedef __attribute__((ext_vector_type(16))) float  f32x16;
typedef __attribute__((ext_vector_type(2)))  unsigned uint2v;

__device__ __forceinline__ __bf16 to_bf16(float f) { return (__bf16)f; }

__device__ __forceinline__ unsigned pack2(float lo, float hi) {
    union { __bf16 h; unsigned short u; } a, b;
    a.h = (__bf16)lo; b.h = (__bf16)hi;
    return (unsigned)a.u | ((unsigned)b.u << 16);
}

// ---------------- fused fp32 -> bf16 convert: x then ctx in one flat grid ----------------
__global__ __launch_bounds__(256)
void cvt_all(const float* __restrict__ x, const float* __restrict__ ctx,
             __bf16* __restrict__ xb, __bf16* __restrict__ cb)
{
    const int nx = (B_ * N_ * QD_) / 4;
    const int nc = (B_ * J_ * CD_) / 4;
    int i = blockIdx.x * 256 + threadIdx.x;
    if (i < nx) {
        float4 v = ((const float4*)x)[i];
        bf16x4 o;
        o[0] = (__bf16)v.x; o[1] = (__bf16)v.y; o[2] = (__bf16)v.z; o[3] = (__bf16)v.w;
        ((bf16x4*)xb)[i] = o;
    } else if (i < nx + nc) {
        float4 v = ((const float4*)ctx)[i - nx];
        bf16x4 o;
        o[0] = (__bf16)v.x; o[1] = (__bf16)v.y; o[2] = (__bf16)v.z; o[3] = (__bf16)v.w;
        ((bf16x4*)cb)[i - nx] = o;
    }
}

// ---------------- fused weight transposes: all 4 weights, blockIdx.z selects ----------------
__global__ __launch_bounds__(256)
void transpose_all(const float* __restrict__ Wq, const float* __restrict__ Wk,
                   const float* __restrict__ Wv, const float* __restrict__ Wo,
                   __bf16* __restrict__ wqt, __bf16* __restrict__ wkt,
                   __bf16* __restrict__ wvt, __bf16* __restrict__ wot, float sq)
{
    __shared__ float tile[32][33];
    const int z = blockIdx.z;
    const float* W;  __bf16* Wt;  int K;  float scale = 1.f;
    if (z == 0)      { W = Wq; Wt = wqt; K = QD_;   scale = sq; }
    else if (z == 1) { W = Wk; Wt = wkt; K = CD_; }
    else if (z == 2) { W = Wv; Wt = wvt; K = CD_; }
    else             { W = Wo; Wt = wot; K = INNER_; }
    const int N = 1024;
    const int n0 = blockIdx.x * 32;
    const int k0 = blockIdx.y * 32;
    if (k0 >= K) return;
    const int tx = threadIdx.x & 31;
    const int ty = threadIdx.x >> 5;
#pragma unroll
    for (int r = 0; r < 32; r += 8)
        tile[ty + r][tx] = W[(size_t)(k0 + ty + r) * N + n0 + tx];
    __syncthreads();
#pragma unroll
    for (int r = 0; r < 32; r += 8)
        Wt[(size_t)(n0 + ty + r) * K + k0 + tx] = to_bf16(tile[tx][ty + r] * scale);
}

// ================ 256x256 8-wave pipelined GEMM core (R10 schedule, verified) ==========
template<int FINAL, int KDIM>
__device__ __forceinline__
void core8(const __bf16* __restrict__ A, const __bf16* __restrict__ Bt,
           __bf16* __restrict__ Cb, __bf16* __restrict__ Cb2, float* __restrict__ Cf,
           const float* __restrict__ bias, int N, int work,
           __bf16 (&sA)[2][16384], __bf16 (&sB)[2][16384])
{
    constexpr int NIT = KDIM / 64;

    const int tid = threadIdx.x;
    const int wid = tid >> 6;
    const int l   = tid & 63;
    const int lo  = l & 15, hi = (l >> 4) & 3;

    const int gn = N >> 8;
    const int m0 = (work / gn) * 256;
    const int n0 = (work % gn) * 256;

    const int wm  = (wid >> 2) * 128, wn = (wid & 3) * 64;
    const int wmr = (wid >> 2) * 8,   bnr = (wid & 3) * 4;

    int rOff[2], cOff[2], dOff[2];
#pragma unroll
    for (int n = 0; n < 2; ++n) {
        const int s = n * 8 + wid;
        rOff[n] = (s >> 1) * 16 + (l >> 2);
        cOff[n] = (s & 1) * 32 + (((l & 3) * 8) ^ (((l >> 5) & 1) * 16));
        dOff[n] = n * 4096 + wid * 512;
    }

    const int inner = lo * 32 + ((hi * 8) ^ ((lo >> 3) * 16));

    f32x4 acc[8][4] = {};
    bf16x8 af[4][2], bfr[4][2];

#define STAGE8(nb, h, kt) do { \
    _Pragma("unroll") \
    for (int n = 0; n < 2; ++n) { \
        const __bf16* gp = ((h) < 2 ? A + (size_t)(m0 + ((h) & 1) * 128 + rOff[n]) * KDIM \
                                    : Bt + (size_t)(n0 + ((h) & 1) * 128 + rOff[n]) * KDIM) \
                           + (kt) + cOff[n]; \
        __bf16* dp = ((h) < 2 ? &sA[nb][((h) & 1) * 8192 + dOff[n]] \
                              : &sB[nb][((h) & 1) * 8192 + dOff[n]]); \
        __builtin_amdgcn_global_load_lds((const __attribute__((address_space(1))) void*)gp, \
                                         (__attribute__((address_space(3))) void*)dp, 16, 0, 0); \
    } } while (0)

#define RD_A(x0, cnt, nb) do { \
    _Pragma("unroll") \
    for (int x = 0; x < (cnt); ++x) \
        _Pragma("unroll") \
        for (int kk = 0; kk < 2; ++kk) \
            af[x][kk] = *(const bf16x8*)&sA[nb][((wmr + (x0) + x) * 2 + kk) * 512 + inner]; \
    } while (0)

#define RD_B(j0, cnt, nb) do { \
    _Pragma("unroll") \
    for (int j = 0; j < (cnt); ++j) \
        _Pragma("unroll") \
        for (int kk = 0; kk < 2; ++kk) \
            bfr[(j0) + j][kk] = *(const bf16x8*)&sB[nb][((bnr + (j0) + j) * 2 + kk) * 512 + inner]; \
    } while (0)

#define MMQ(mh, nh) do { \
    __builtin_amdgcn_s_setprio(1); \
    _Pragma("unroll") \
    for (int x = 0; x < 4; ++x) \
        _Pragma("unroll") \
        for (int j = 0; j < 2; ++j) \
            _Pragma("unroll") \
            for (int kk = 0; kk < 2; ++kk) \
                acc[(mh) * 4 + x][(nh) * 2 + j] = __builtin_amdgcn_mfma_f32_16x16x32_bf16( \
                    af[x][kk], bfr[(nh) * 2 + j][kk], acc[(mh) * 4 + x][(nh) * 2 + j], 0, 0, 0); \
    __builtin_amdgcn_s_setprio(0); \
    } while (0)

#define BARR() do { __builtin_amdgcn_s_barrier(); \
    asm volatile("" ::: "memory"); __builtin_amdgcn_sched_barrier(0); } while (0)

#pragma unroll
    for (int h = 0; h < 4; ++h) STAGE8(0, h, 0);

    for (int it = 0; it < NIT; ++it) {
        const int nb = it & 1, nbn = nb ^ 1;
        const int ktn = (it + 1) * 64;
        const bool notlast = (it < NIT - 1);

        if (notlast) STAGE8(nbn, 0, ktn);
        if (notlast) asm volatile("s_waitcnt vmcnt(2)" ::: "memory");
        else         asm volatile("s_waitcnt vmcnt(0)" ::: "memory");
        BARR();
        RD_A(0, 4, nb); RD_B(0, 2, nb);
        MMQ(0, 0);
        BARR();
        if (notlast) STAGE8(nbn, 1, ktn);
        BARR();
        RD_B(2, 2, nb);
        MMQ(0, 1);
        BARR();
        if (notlast) STAGE8(nbn, 2, ktn);
        BARR();
        RD_A(4, 4, nb);
        MMQ(1, 0);
        BARR();
        if (notlast) STAGE8(nbn, 3, ktn);
        BARR();
        MMQ(1, 1);
        BARR();
    }
#undef STAGE8
#undef RD_A
#undef RD_B
#undef MMQ
#undef BARR

#pragma unroll
    for (int i = 0; i < 8; ++i) {
        const int row = m0 + wm + i * 16 + hi * 4;
#pragma unroll
        for (int j = 0; j < 4; ++j) {
            const int col = n0 + wn + j * 16 + lo;
            if (FINAL == 3) {
                if (col < 1024) {
#pragma unroll
                    for (int r = 0; r < 4; ++r)
                        Cb[(size_t)(row + r) * 1024 + col] = to_bf16(acc[i][j][r]);
                } else {
                    const int c2 = col - 1024;
                    const int head = c2 >> 6, d = c2 & 63;
                    const int bb = row >> 10, jj = row & 1023;
                    bf16x4 v4;
#pragma unroll
                    for (int r = 0; r < 4; ++r) v4[r] = to_bf16(acc[i][j][r]);
                    *(bf16x4*)&Cb2[(((size_t)(bb * 16 + head)) * 64 + d) * (size_t)J_ + jj] = v4;
                }
            } else {
#pragma unroll
                for (int r = 0; r < 4; ++r) {
                    if (FINAL == 1) Cf[(size_t)(row + r) * N + col] = acc[i][j][r] + bias[col];
                    else            Cb[(size_t)(row + r) * N + col] = to_bf16(acc[i][j][r]);
                }
            }
        }
    }
}

// Merged Q-proj + KV-proj: blocks 0-255 -> Q (xb*wqt), 256-511 -> KV (cb*[wkt||wvt]).
// Each half XCD-chunked (hb&7 = XCD, 32 contiguous works per XCD -> A-panels L2-resident).
__global__ __launch_bounds__(512, 2)
void gemm_qkv(const __bf16* __restrict__ xb, const __bf16* __restrict__ wqt, __bf16* __restrict__ Qb,
              const __bf16* __restrict__ cb, const __bf16* __restrict__ wkt,
              __bf16* __restrict__ Kb, __bf16* __restrict__ Vt)
{
    __shared__ __bf16 sA[2][16384];
    __shared__ __bf16 sB[2][16384];
    const int blk = blockIdx.x;
    if (blk < 256) {
        const int work = (blk & 7) * 32 + (blk >> 3);
        core8<0, QD_>(xb, wqt, Qb, nullptr, nullptr, nullptr, INNER_, work, sA, sB);
    } else {
        const int hb = blk - 256;
        const int work = (hb & 7) * 32 + (hb >> 3);
        core8<3, CD_>(cb, wkt, Kb, Vt, nullptr, nullptr, 2 * INNER_, work, sA, sB);
    }
}

// O-projection: fp32 + bias, XCD-chunked.
__global__ __launch_bounds__(512, 2)
void gemm_o(const __bf16* __restrict__ Ob, const __bf16* __restrict__ wot,
            float* __restrict__ out, const float* __restrict__ bias)
{
    __shared__ __bf16 sA[2][16384];
    __shared__ __bf16 sB[2][16384];
    const int blk = blockIdx.x;
    const int work = (blk & 7) * 32 + (blk >> 3);
    core8<1, INNER_>(Ob, wot, nullptr, nullptr, out, bias, QD_, work, sA, sB);
}

// ---------------- attention (frozen: R11 structure + 4 blocks/CU) ----------------
#define SEGE 544

__global__ __launch_bounds__(256, 4)
void attn2(const __bf16* __restrict__ Qb, const __bf16* __restrict__ Kb,
           const __bf16* __restrict__ Vt, __bf16* __restrict__ Ob)
{
    __shared__ __bf16 sK[2][8 * SEGE];
    __shared__ __bf16 sV[2][8 * SEGE];

    const int tid = threadIdx.x;
    const int wid = tid >> 6;
    const int l   = tid & 63;
    const int lq  = l & 31;
    const int hi  = l >> 5;

    const int blk  = blockIdx.x;
    const int work = (blk & 7) * 256 + (blk >> 3);
    const int qt = work & 15;
    const int h  = (work >> 4) & 15;
    const int b  = work >> 8;
    const int bh = b * H_ + h;

    bf16x8 qf[4];
    {
        const __bf16* qp = Qb + ((size_t)b * N_ + qt * 128 + wid * 32 + lq) * INNER_ + h * D_;
#pragma unroll
        for (int kc = 0; kc < 4; ++kc)
            qf[kc] = *(const bf16x8*)(qp + kc * 16 + hi * 8);
    }

    f32x16 accO[2] = {};
    float lsum = 0.f;

    const int srow = l >> 3, schk = l & 7;
    const __bf16* ksrc = Kb + ((size_t)b * J_ + wid * 8 + srow) * INNER_ + h * D_ + ((schk ^ srow) * 8);
    const __bf16* vsrc = Vt + ((size_t)bh * D_ + wid * 8 + srow) * J_ + ((schk ^ srow) * 8);

#define STAGE_T(bb, t) do { \
    _Pragma("unroll") \
    for (int c = 0; c < 2; ++c) { \
        __builtin_amdgcn_global_load_lds((const __attribute__((address_space(1))) void*)(ksrc + ((size_t)(t) * 64 + c * 32) * INNER_), \
            (__attribute__((address_space(3))) void*)(&sK[bb][(c * 4 + wid) * SEGE]), 16, 0, 0); \
        __builtin_amdgcn_global_load_lds((const __attribute__((address_space(1))) void*)(vsrc + (size_t)(c) * 32 * J_ + (t) * 64), \
            (__attribute__((address_space(3))) void*)(&sV[bb][(c * 4 + wid) * SEGE]), 16, 0, 0); \
    } } while (0)

    STAGE_T(0, 0);
    __syncthreads();

    for (int t = 0; t < J_ / 64; ++t) {
        const int bb = t & 1;
        if (t < J_ / 64 - 1) STAGE_T(bb ^ 1, t + 1);

        const __bf16* Ks = sK[bb];
        const __bf16* Vs = sV[bb];

#pragma unroll
        for (int jsub = 0; jsub < 2; ++jsub) {
            bf16x8 kf[4], vf[2][2];
            const int ksg = (jsub * 4 + (lq >> 3)) * SEGE + (lq & 7) * 64;
#pragma unroll
            for (int kc = 0; kc < 4; ++kc)
                kf[kc] = *(const bf16x8*)&Ks[ksg + (((kc * 2 + hi) ^ (lq & 7)) * 8)];
#pragma unroll
            for (int dt = 0; dt < 2; ++dt) {
                const int vsg = (dt * 4 + (lq >> 3)) * SEGE + (lq & 7) * 64;
#pragma unroll
                for (int k2 = 0; k2 < 2; ++k2)
                    vf[dt][k2] = *(const bf16x8*)&Vs[vsg + ((((jsub * 2 + k2) * 2 + hi) ^ (lq & 7)) * 8)];
            }

            f32x16 s = {};
            __builtin_amdgcn_s_setprio(1);
#pragma unroll
            for (int kc = 0; kc < 4; ++kc)
                s = __builtin_amdgcn_mfma_f32_32x32x16_bf16(kf[kc], qf[kc], s, 0, 0, 0);
            __builtin_amdgcn_s_setprio(0);

            float p[16];
#pragma unroll
            for (int r = 0; r < 16; ++r)
                p[r] = __builtin_amdgcn_exp2f(s[r]);
            {
                float t0 = (p[0] + p[1]) + (p[2] + p[3]);
                float t1 = (p[4] + p[5]) + (p[6] + p[7]);
                float t2 = (p[8] + p[9]) + (p[10] + p[11]);
                float t3 = (p[12] + p[13]) + (p[14] + p[15]);
                lsum += (t0 + t1) + (t2 + t3);
            }

#pragma unroll
            for (int k2 = 0; k2 < 2; ++k2) {
                unsigned a0 = pack2(p[k2 * 8 + 0], p[k2 * 8 + 1]);
                unsigned a1 = pack2(p[k2 * 8 + 2], p[k2 * 8 + 3]);
                unsigned b0 = pack2(p[k2 * 8 + 4], p[k2 * 8 + 5]);
                unsigned b1 = pack2(p[k2 * 8 + 6], p[k2 * 8 + 7]);
                uint2v r0 = __builtin_amdgcn_permlane32_swap(a0, b0, false, false);
                uint2v r1 = __builtin_amdgcn_permlane32_swap(a1, b1, false, false);
                union { unsigned u[4]; bf16x8 v; } pu;
                pu.u[0] = r0[0];
                pu.u[1] = r1[0];
                pu.u[2] = r0[1];
                pu.u[3] = r1[1];
                __builtin_amdgcn_s_setprio(1);
#pragma unroll
                for (int dt = 0; dt < 2; ++dt)
                    accO[dt] = __builtin_amdgcn_mfma_f32_32x32x16_bf16(vf[dt][k2], pu.v, accO[dt], 0, 0, 0);
                __builtin_amdgcn_s_setprio(0);
            }
        }
        __syncthreads();
    }
#undef STAGE_T

    {
        float lt = lsum + __shfl_xor(lsum, 32);
        float inv = 1.f / lt;
        __bf16* op = Ob + ((size_t)b * N_ + qt * 128 + wid * 32 + lq) * INNER_ + h * D_;
#pragma unroll
        for (int dt = 0; dt < 2; ++dt)
#pragma unroll
            for (int g = 0; g < 4; ++g) {
                bf16x4 v4;
#pragma unroll
                for (int e = 0; e < 4; ++e) v4[e] = to_bf16(accO[dt][g * 4 + e] * inv);
                *(bf16x4*)&op[dt * 32 + g * 8 + hi * 4] = v4;
            }
    }
}

// ---------------- host ----------------
extern "C" void kernel_launch(void* const* d_in, const int* in_sizes, int n_in,
                              void* d_out, int out_size, void* d_ws, size_t ws_size,
                              hipStream_t stream)
{
    const float* x   = (const float*)d_in[0];
    const float* ctx = (const float*)d_in[1];
    const float* Wq  = (const float*)d_in[2];
    const float* Wk  = (const float*)d_in[3];
    const float* Wv  = (const float*)d_in[4];
    const float* Wo  = (const float*)d_in[5];
    const float* bo  = (const float*)d_in[6];
    float* out = (float*)d_out;

    char* w = (char*)d_ws;
    auto take = [&](size_t bytes) { char* p = w; w += bytes; return p; };
    __bf16* xb  = (__bf16*)take((size_t)B_ * N_ * QD_ * 2);
    __bf16* cb  = (__bf16*)take((size_t)B_ * J_ * CD_ * 2);
    __bf16* wqt = (__bf16*)take((size_t)QD_ * INNER_ * 2);
    __bf16* wkt = (__bf16*)take((size_t)CD_ * INNER_ * 2);   // wkt+wvt adjacent
    __bf16* wvt = (__bf16*)take((size_t)CD_ * INNER_ * 2);
    __bf16* wot = (__bf16*)take((size_t)INNER_ * QD_ * 2);
    __bf16* Qb  = (__bf16*)take((size_t)B_ * N_ * INNER_ * 2);
    __bf16* Kb  = (__bf16*)take((size_t)B_ * J_ * INNER_ * 2);
    __bf16* Vt  = (__bf16*)take((size_t)B_ * J_ * INNER_ * 2);
    __bf16* Ob  = xb;

    const float SCALE_Q = 0.125f * 1.44269504088896f;

    const int ncvt = (B_ * N_ * QD_ + B_ * J_ * CD_) / 4;
    cvt_all<<<(ncvt + 255) / 256, 256, 0, stream>>>(x, ctx, xb, cb);
    transpose_all<<<dim3(32, 32, 4), 256, 0, stream>>>(Wq, Wk, Wv, Wo, wqt, wkt, wvt, wot, SCALE_Q);

    gemm_qkv<<<512, 512, 0, stream>>>(xb, wqt, Qb, cb, wkt, Kb, Vt);

    attn2<<<(N_ / 128) * H_ * B_, 256, 0, stream>>>(Qb, Kb, Vt, Ob);

    gemm_o<<<256, 512, 0, stream>>>(Ob, wot, out, bo);
}